// Round 4
// baseline (5365.331 us; speedup 1.0000x reference)
//
#include <hip/hip_runtime.h>
#include <stdint.h>

#define GF_ACC   1
#define GF_BIAS  2
#define GF_RELU  8

#define BM 128
#define BN 128
#define BK 16

// ---------------- CSR build ----------------

__global__ void deg_count_kernel(const int* __restrict__ src, const int* __restrict__ dst,
                                 const float* __restrict__ ew,
                                 float* __restrict__ deg, int* __restrict__ cnt, int E)
{
    int e = blockIdx.x * blockDim.x + threadIdx.x;
    if (e < E) {
        int d = dst[e];
        atomicAdd(&deg[d], ew[e]);
        atomicAdd(&cnt[d], 1);
    }
}

__global__ void dis_kernel(const float* __restrict__ deg, float* __restrict__ dis, int n)
{
    int i = blockIdx.x * blockDim.x + threadIdx.x;
    if (i < n) {
        float d = deg[i];
        dis[i] = (d > 0.f) ? (1.0f / sqrtf(d)) : 0.f;
    }
}

__global__ __launch_bounds__(1024) void scan_kernel(int* __restrict__ cnt_cursor,
                                                    int* __restrict__ row_ptr, int n)
{
    __shared__ int wsum[16];
    __shared__ int s_carry;
    if (threadIdx.x == 0) s_carry = 0;
    __syncthreads();
    const int VT = 8;
    const int CHUNK = 1024 * VT;
    int lane = threadIdx.x & 63;
    int wid = threadIdx.x >> 6;
    for (int base = 0; base < n; base += CHUNK) {
        int v[VT];
        int idx0 = base + threadIdx.x * VT;
        int tsum = 0;
#pragma unroll
        for (int t = 0; t < VT; t++) {
            int i = idx0 + t;
            v[t] = (i < n) ? cnt_cursor[i] : 0;
            tsum += v[t];
        }
        int incl = tsum;
        for (int off = 1; off < 64; off <<= 1) {
            int t = __shfl_up(incl, off);
            if (lane >= off) incl += t;
        }
        if (lane == 63) wsum[wid] = incl;
        __syncthreads();
        if (wid == 0) {
            int wv = (lane < 16) ? wsum[lane] : 0;
            for (int off = 1; off < 16; off <<= 1) {
                int t = __shfl_up(wv, off);
                if (lane >= off) wv += t;
            }
            if (lane < 16) wsum[lane] = wv;
        }
        __syncthreads();
        int wave_off = (wid > 0) ? wsum[wid - 1] : 0;
        int excl = incl - tsum + wave_off + s_carry;
#pragma unroll
        for (int t = 0; t < VT; t++) {
            int i = idx0 + t;
            if (i < n) {
                cnt_cursor[i] = excl;
                row_ptr[i + 1] = excl + v[t];
            }
            excl += v[t];
        }
        __syncthreads();
        if (threadIdx.x == 0) s_carry += wsum[15];
        __syncthreads();
    }
    if (threadIdx.x == 0) row_ptr[0] = 0;
}

__global__ void scatter_kernel(const int* __restrict__ src, const int* __restrict__ dst,
                               const float* __restrict__ ew, const float* __restrict__ dis,
                               int* __restrict__ cursor, int2* __restrict__ e2, int E)
{
    int e = blockIdx.x * blockDim.x + threadIdx.x;
    if (e < E) {
        int s = src[e], d = dst[e];
        int pos = atomicAdd(&cursor[d], 1);
        float nw = dis[s] * ew[e] * dis[d];
        e2[pos] = make_int2(s, __float_as_int(nw));
    }
}

// ---------------- propagation ----------------

__global__ __launch_bounds__(256) void prop1(const float* __restrict__ xv, const float* __restrict__ z,
                                             float* __restrict__ y, const int* __restrict__ rp,
                                             const int2* __restrict__ e2, int n, int mode)
{
    int node = blockIdx.x * 64 + (threadIdx.x >> 2);
    if (node >= n) return;
    int g = threadIdx.x & 3;
    int e0 = rp[node], e1 = rp[node + 1];
    float acc = 0.f;
    for (int e = e0 + g; e < e1; e += 4) {
        int2 q = e2[e];
        acc += __int_as_float(q.y) * xv[q.x];
    }
    acc += __shfl_xor(acc, 1);
    acc += __shfl_xor(acc, 2);
    if (g == 0) {
        if (z) acc += z[node];
        if (mode == 1) acc = 1.0f / (1.0f + expf(-acc));
        y[node] = acc;
    }
}

// wide propagation: wave per node; lane = (edge_sub, col4); float4 gathers, 4x edge unroll.
template<int C4, int EPW, bool HASZ, bool RELU>
__global__ __launch_bounds__(256) void propw(const float* __restrict__ X, int xstr,
                                             const float* __restrict__ Z, int zstr,
                                             float* __restrict__ Y, int ystr,
                                             const int* __restrict__ rp,
                                             const int2* __restrict__ e2, int n)
{
    int node = blockIdx.x * 4 + (threadIdx.x >> 6);
    if (node >= n) return;
    int lane = threadIdx.x & 63;
    int c4 = lane % C4;
    int e_sub = lane / C4;
    bool active = (lane < C4 * EPW);
    int e0 = rp[node], e1 = rp[node + 1];
    float ax = 0.f, ay = 0.f, az = 0.f, aw = 0.f;
    for (int base = e0; base < e1; base += EPW * 4) {
        int sv[4]; float wv[4];
#pragma unroll
        for (int u = 0; u < 4; u++) {
            int eid = base + u * EPW + e_sub;
            bool ok = active && (eid < e1);
            int2 q = ok ? e2[eid] : make_int2(0, 0);
            sv[u] = q.x;
            wv[u] = __int_as_float(q.y);
        }
        float4 xq[4];
#pragma unroll
        for (int u = 0; u < 4; u++)
            xq[u] = *(const float4*)(X + (size_t)sv[u] * xstr + 4 * c4);
#pragma unroll
        for (int u = 0; u < 4; u++) {
            ax += wv[u] * xq[u].x; ay += wv[u] * xq[u].y;
            az += wv[u] * xq[u].z; aw += wv[u] * xq[u].w;
        }
    }
    float ox = ax, oy = ay, oz = az, ow = aw;
#pragma unroll
    for (int g = 1; g < EPW; g++) {
        int sl = c4 + g * C4;
        ax += __shfl(ox, sl); ay += __shfl(oy, sl);
        az += __shfl(oz, sl); aw += __shfl(ow, sl);
    }
    if (lane < C4) {
        if (HASZ) {
            float4 zq = *(const float4*)(Z + (size_t)node * zstr + 4 * c4);
            ax += zq.x; ay += zq.y; az += zq.z; aw += zq.w;
        }
        if (RELU) {
            ax = fmaxf(ax, 0.f); ay = fmaxf(ay, 0.f);
            az = fmaxf(az, 0.f); aw = fmaxf(aw, 0.f);
        }
        float4 o = { ax, ay, az, aw };
        *(float4*)(Y + (size_t)node * ystr + 4 * c4) = o;
    }
}

// ---------------- GEMM ----------------
// 128x128 tile, 8x8 microtile. W tile split into two 64-col LDS arrays so the
// tx-strided b128 reads are 2-way (free) instead of 4-way conflicted.
__global__ __launch_bounds__(256) void gemm2(
    const float* __restrict__ X, int x_sn, int x_sk,
    const float* __restrict__ W, int w_sk, int w_sc,
    const float* __restrict__ bias,
    float* __restrict__ out, int o_sn, int o_sc,
    int M, int K, int NC, int flags, int bias_cols)
{
    __shared__ float Xs[BK][BM + 4];
    __shared__ float WsA[BK][68];
    __shared__ float WsB[BK][68];
    int tid = threadIdx.x;
    int bm = blockIdx.x * BM;
    int bn = blockIdx.y * BN;
    int tx = tid & 15, ty = tid >> 4;
    float acc[8][8] = {};
    bool xvec = (x_sk == 1) && ((x_sn & 3) == 0) && (bm + BM <= M);
    bool wvec = (w_sc == 1) && ((w_sk & 3) == 0) && (bn + BN <= NC);
    for (int k0 = 0; k0 < K; k0 += BK) {
        bool fullk = (k0 + BK <= K);
        if (xvec && fullk) {
#pragma unroll
            for (int h = 0; h < 2; h++) {
                int u = tid + 256 * h;
                int row = u >> 2;
                int kq = (u & 3) * 4;
                float4 q = *(const float4*)(X + (size_t)(bm + row) * x_sn + k0 + kq);
                Xs[kq + 0][row] = q.x; Xs[kq + 1][row] = q.y;
                Xs[kq + 2][row] = q.z; Xs[kq + 3][row] = q.w;
            }
        } else {
            int xk = tid & 15, xm0 = tid >> 4;
#pragma unroll
            for (int r = 0; r < 8; r++) {
                int m = xm0 + 16 * r;
                int gm = bm + m, gk = k0 + xk;
                Xs[xk][m] = (gm < M && gk < K) ? X[(size_t)gm * x_sn + (size_t)gk * x_sk] : 0.f;
            }
        }
        if (wvec && fullk) {
#pragma unroll
            for (int h = 0; h < 2; h++) {
                int u = tid + 256 * h;
                int wk = u >> 5;
                int wc = (u & 31) * 4;
                float4 q = *(const float4*)(W + (size_t)(k0 + wk) * w_sk + bn + wc);
                if (wc < 64) *(float4*)&WsA[wk][wc] = q;
                else         *(float4*)&WsB[wk][wc - 64] = q;
            }
        } else {
            int wk = tid >> 4;
            int c0 = (tid & 15) * 8;
#pragma unroll
            for (int j = 0; j < 8; j++) {
                int c = c0 + j;
                int gk = k0 + wk, gc = bn + c;
                float v = (gk < K && gc < NC) ? W[(size_t)gk * w_sk + (size_t)gc * w_sc] : 0.f;
                if (c < 64) WsA[wk][c] = v; else WsB[wk][c - 64] = v;
            }
        }
        __syncthreads();
#pragma unroll
        for (int kk = 0; kk < BK; kk++) {
            float xv[8], wv[8];
#pragma unroll
            for (int i = 0; i < 8; i++) xv[i] = Xs[kk][ty * 8 + i];
#pragma unroll
            for (int j = 0; j < 4; j++) { wv[j] = WsA[kk][tx * 4 + j]; wv[4 + j] = WsB[kk][tx * 4 + j]; }
#pragma unroll
            for (int i = 0; i < 8; i++)
#pragma unroll
                for (int j = 0; j < 8; j++)
                    acc[i][j] += xv[i] * wv[j];
        }
        __syncthreads();
    }
#pragma unroll
    for (int i = 0; i < 8; i++) {
        int gm = bm + ty * 8 + i;
        if (gm >= M) continue;
#pragma unroll
        for (int h = 0; h < 2; h++) {
            int c0 = bn + 64 * h + tx * 4;
            bool ovec = (o_sc == 1) && ((o_sn & 3) == 0) && (c0 + 3 < NC);
            if (ovec) {
                float* op = out + (size_t)gm * o_sn + c0;
                float4 v = { acc[i][h * 4 + 0], acc[i][h * 4 + 1], acc[i][h * 4 + 2], acc[i][h * 4 + 3] };
                if (flags & GF_ACC) {
                    float4 o = *(const float4*)op;
                    v.x += o.x; v.y += o.y; v.z += o.z; v.w += o.w;
                }
                if (flags & GF_BIAS) {
#pragma unroll
                    for (int j = 0; j < 4; j++) {
                        int gc = c0 + j;
                        if (gc < bias_cols) (&v.x)[j] += bias[gc];
                    }
                }
                if (flags & GF_RELU) {
                    v.x = fmaxf(v.x, 0.f); v.y = fmaxf(v.y, 0.f);
                    v.z = fmaxf(v.z, 0.f); v.w = fmaxf(v.w, 0.f);
                }
                *(float4*)op = v;
            } else {
#pragma unroll
                for (int j = 0; j < 4; j++) {
                    int gc = c0 + j;
                    if (gc >= NC) continue;
                    size_t oi = (size_t)gm * o_sn + (size_t)gc * o_sc;
                    float v = acc[i][h * 4 + j];
                    if (flags & GF_ACC)  v += out[oi];
                    if ((flags & GF_BIAS) && gc < bias_cols) v += bias[gc];
                    if (flags & GF_RELU) v = fmaxf(v, 0.f);
                    out[oi] = v;
                }
            }
        }
    }
}

// W4 [21,200,80] -> W4t [200, 21*80] with col = hop*80+co
__global__ void w4t_kernel(const float* __restrict__ w, float* __restrict__ wt, int total)
{
    int t = blockIdx.x * blockDim.x + threadIdx.x;
    if (t >= total) return;
    int oc = t % 1680, cin = t / 1680;
    int hop = oc / 80, co = oc % 80;
    wt[t] = w[hop * 16000 + cin * 80 + co];
}

// pack W [hops, Cin, Cout] into Wp [(hops*slot), Cout] with zero rows at slot pads
__global__ void pack_w(const float* __restrict__ w, float* __restrict__ wp,
                       int Cin, int Cout, int slot, int total)
{
    int t = blockIdx.x * blockDim.x + threadIdx.x;
    if (t >= total) return;
    int co = t % Cout;
    int rc = t / Cout;
    int c = rc % slot, j = rc / slot;
    wp[t] = (c < Cin) ? w[((size_t)j * Cin + c) * Cout + co] : 0.f;
}

// ---------------- launch ----------------

extern "C" void kernel_launch(void* const* d_in, const int* in_sizes, int n_in,
                              void* d_out, int out_size, void* d_ws, size_t ws_size,
                              hipStream_t stream)
{
    const int N = 50000, E = 800000, K = 20;
    const float* x  = (const float*)d_in[0];
    const int*   ei = (const int*)d_in[1];
    const float* ew = (const float*)d_in[2];
    const float* Wl[5]; const float* bl[5];
    for (int l = 0; l < 5; l++) { Wl[l] = (const float*)d_in[3 + 2 * l]; bl[l] = (const float*)d_in[4 + 2 * l]; }
    const int* src = ei;
    const int* dst = ei + E;
    (void)in_sizes; (void)n_in; (void)out_size;

    uintptr_t base = (uintptr_t)d_ws;
    uintptr_t cur = base;
    auto alloc = [&](size_t bytes) -> char* {
        uintptr_t q = (cur + 255) & ~(uintptr_t)255;
        cur = q + bytes;
        return (char*)q;
    };
    float* deg    = (float*)alloc((size_t)N * 4);
    float* dis    = (float*)alloc((size_t)N * 4);
    int*   rowptr = (int*)alloc((size_t)(N + 1) * 4);
    int*   cursor = (int*)alloc((size_t)N * 4);
    int2*  e2     = (int2*)alloc((size_t)E * 8);
    float* Zb     = (float*)alloc((size_t)(K + 1) * N * 4);  // [21, N] hop-major
    float* ya     = (float*)alloc((size_t)N * 4);
    float* yb     = (float*)alloc((size_t)N * 4);
    float* h1     = (float*)alloc((size_t)N * 64 * 4);   // stride 64 (padded, gathered)
    float* h2     = (float*)alloc((size_t)N * 100 * 4);
    float* h3     = (float*)alloc((size_t)N * 200 * 4);
    float* h4     = (float*)alloc((size_t)N * 80 * 4);
    float* Ra     = (float*)alloc((size_t)N * 96 * 4);   // stride 96 (padded, gathered)
    float* Rb     = (float*)alloc((size_t)N * 96 * 4);
    float* W4t    = (float*)alloc((size_t)200 * 1680 * 4);
    float* Wp     = (float*)alloc((size_t)20 * 64 * 100 * 4);

    // adaptive hop-batch arena
    size_t used = (size_t)(cur - base);
    size_t avail = (ws_size > used + (1 << 20)) ? (ws_size - used - (1 << 20)) : 0;
    size_t cap = (size_t)N * 2000 * 4;   // 400 MB = full 20-slot C=100 stack
    size_t arena_bytes = avail < cap ? avail : cap;
    float* Sb = (float*)alloc(arena_bytes);
    auto clampH = [&](int slotw, int hi) {
        long h = (long)(arena_bytes / ((size_t)N * slotw * 4));
        if (h < 1) h = 1;
        if (h > hi) h = hi;
        return (int)h;
    };
    const int H2s = clampH(64, K);       // L2 stack slots (width 64, 60 used)
    const int H3s = clampH(100, K);      // L3 stack slots
    const int B4s = clampH(80, K + 1);   // L4 Z-batch slots
    const int rowstr2 = H2s * 64;
    const int rowstr3 = H3s * 100;
    const int rowstr4 = B4s * 80;

    // ---- CSR build
    hipMemsetAsync(deg, 0, (size_t)N * 4, stream);
    hipMemsetAsync(cursor, 0, (size_t)N * 4, stream);
    deg_count_kernel<<<(E + 255) / 256, 256, 0, stream>>>(src, dst, ew, deg, cursor, E);
    dis_kernel<<<(N + 255) / 256, 256, 0, stream>>>(deg, dis, N);
    scan_kernel<<<1, 1024, 0, stream>>>(cursor, rowptr, N);
    scatter_kernel<<<(E + 255) / 256, 256, 0, stream>>>(src, dst, ew, dis, cursor, e2, E);

    const int PB = (N + 63) / 64;
    const int WB = (N + 3) / 4;
    const int GMX = (N + BM - 1) / BM;

    // ---- Layer 1 (1 -> 60): width-1 chain into Zb, one GEMM K=21
    hipMemcpyAsync(Zb, x, (size_t)N * 4, hipMemcpyDeviceToDevice, stream);
    for (int k = 1; k <= K; k++)
        prop1<<<PB, 256, 0, stream>>>(Zb + (size_t)(k - 1) * N, nullptr, Zb + (size_t)k * N,
                                      rowptr, e2, N, 0);
    gemm2<<<dim3(GMX, 1), 256, 0, stream>>>(Zb, 1, N, Wl[0], 60, 1, bl[0],
                                            h1, 64, 1, N, K + 1, 60, GF_BIAS | GF_RELU, 60);

    // ---- Layer 2 (60 -> 100): hop-batched stack (padded slots) + long-K GEMM w/ padded W
    gemm2<<<dim3(GMX, 1), 256, 0, stream>>>(h1, 64, 1, Wl[1], 100, 1, bl[1],
                                            h2, 100, 1, N, 60, 100, GF_BIAS, 100);
    {
        int done = 0;
        const float* prevp = h1; int prevstr = 64;
        while (done < K) {
            int H = (K - done < H2s) ? (K - done) : H2s;
            for (int j = 0; j < H; j++) {
                float* dstp = Sb + j * 64;
                propw<15, 4, false, false><<<WB, 256, 0, stream>>>(prevp, prevstr, nullptr, 0,
                    dstp, rowstr2, rowptr, e2, N);
                prevp = dstp; prevstr = rowstr2;
            }
            int tot = H * 64 * 100;
            pack_w<<<(tot + 255) / 256, 256, 0, stream>>>(Wl[1] + (size_t)(1 + done) * 6000, Wp,
                                                          60, 100, 64, tot);
            bool last = (done + H == K);
            gemm2<<<dim3(GMX, 1), 256, 0, stream>>>(Sb, rowstr2, 1, Wp, 100, 1, nullptr,
                h2, 100, 1, N, H * 64, 100, GF_ACC | (last ? GF_RELU : 0), 0);
            done += H;
        }
    }

    // ---- Layer 3 (100 -> 200): hop-batched stack (no pad) + long-K GEMM
    gemm2<<<dim3(GMX, 2), 256, 0, stream>>>(h2, 100, 1, Wl[2], 200, 1, bl[2],
                                            h3, 200, 1, N, 100, 200, GF_BIAS, 200);
    {
        int done = 0;
        const float* prevp = h2; int prevstr = 100;
        while (done < K) {
            int H = (K - done < H3s) ? (K - done) : H3s;
            for (int j = 0; j < H; j++) {
                float* dstp = Sb + j * 100;
                propw<25, 2, false, false><<<WB, 256, 0, stream>>>(prevp, prevstr, nullptr, 0,
                    dstp, rowstr3, rowptr, e2, N);
                prevp = dstp; prevstr = rowstr3;
            }
            bool last = (done + H == K);
            gemm2<<<dim3(GMX, 2), 256, 0, stream>>>(Sb, rowstr3, 1,
                Wl[2] + (size_t)(1 + done) * 20000, 200, 1, nullptr,
                h3, 200, 1, N, H * 100, 200, GF_ACC | (last ? GF_RELU : 0), 0);
            done += H;
        }
    }

    // ---- Layer 4 (200 -> 80): batched Z pre-GEMM + Horner width-80 (R padded to 96)
    w4t_kernel<<<(336000 + 255) / 256, 256, 0, stream>>>(Wl[3], W4t, 336000);
    {
        const float* curR = nullptr; int curstr = 0;
        int k_hi = K;
        while (k_hi >= 0) {
            int k_lo = k_hi - B4s + 1; if (k_lo < 0) k_lo = 0;
            int nb = k_hi - k_lo + 1;
            int gy = (nb * 80 + BN - 1) / BN;
            gemm2<<<dim3(GMX, gy), 256, 0, stream>>>(h3, 200, 1, W4t + (size_t)k_lo * 80, 1680, 1,
                bl[3], Sb, rowstr4, 1, N, 200, nb * 80,
                (k_lo == 0) ? GF_BIAS : 0, 80);
            int kstart;
            if (k_hi == K) { curR = Sb + (size_t)(K - k_lo) * 80; curstr = rowstr4; kstart = K - 1; }
            else kstart = k_hi;
            for (int k = kstart; k >= k_lo; k--) {
                const float* Zp = Sb + (size_t)(k - k_lo) * 80;
                if (k == 0) {
                    propw<20, 3, true, true><<<WB, 256, 0, stream>>>(curR, curstr, Zp, rowstr4,
                        h4, 80, rowptr, e2, N);
                } else {
                    float* o = (k & 1) ? Ra : Rb;
                    propw<20, 3, true, false><<<WB, 256, 0, stream>>>(curR, curstr, Zp, rowstr4,
                        o, 96, rowptr, e2, N);
                    curR = o; curstr = 96;
                }
            }
            k_hi = k_lo - 1;
        }
    }

    // ---- Layer 5 (80 -> 1): Z5 [21, N] hop-major, Horner width-1 with sigmoid
    gemm2<<<dim3(GMX, 1), 256, 0, stream>>>(h4, 80, 1, Wl[4], 1, 80, bl[4],
                                            Zb, 1, N, N, 80, K + 1, GF_BIAS, 1);
    const float* cur5 = Zb + (size_t)K * N;
    float* outp = (float*)d_out;
    for (int k = K - 1; k >= 0; k--) {
        float* o = (k == 0) ? outp : ((k & 1) ? ya : yb);
        prop1<<<PB, 256, 0, stream>>>(cur5, Zb + (size_t)k * N, o,
                                      rowptr, e2, N, (k == 0) ? 1 : 0);
        cur5 = o;
    }
}

// Round 7
// 4393.659 us; speedup vs baseline: 1.2212x; 1.2212x over previous
//
#include <hip/hip_runtime.h>
#include <stdint.h>

#define GF_ACC   1
#define GF_BIAS  2
#define GF_RELU  8

#define BM 128
#define BN 64
#define BK 16

typedef short bf16x8 __attribute__((ext_vector_type(8)));
typedef float f32x4 __attribute__((ext_vector_type(4)));
typedef unsigned short u16x8 __attribute__((ext_vector_type(8)));

// ---------------- CSR build ----------------

__global__ void deg_count_kernel(const int* __restrict__ src, const int* __restrict__ dst,
                                 const float* __restrict__ ew,
                                 float* __restrict__ deg, int* __restrict__ cnt, int E)
{
    int e = blockIdx.x * blockDim.x + threadIdx.x;
    if (e < E) {
        int d = dst[e];
        atomicAdd(&deg[d], ew[e]);
        atomicAdd(&cnt[d], 1);
    }
}

__global__ void dis_kernel(const float* __restrict__ deg, float* __restrict__ dis, int n)
{
    int i = blockIdx.x * blockDim.x + threadIdx.x;
    if (i < n) {
        float d = deg[i];
        dis[i] = (d > 0.f) ? (1.0f / sqrtf(d)) : 0.f;
    }
}

__global__ __launch_bounds__(1024) void scan_kernel(int* __restrict__ cnt_cursor,
                                                    int* __restrict__ row_ptr, int n)
{
    __shared__ int wsum[16];
    __shared__ int s_carry;
    if (threadIdx.x == 0) s_carry = 0;
    __syncthreads();
    const int VT = 8;
    const int CHUNK = 1024 * VT;
    int lane = threadIdx.x & 63;
    int wid = threadIdx.x >> 6;
    for (int base = 0; base < n; base += CHUNK) {
        int v[VT];
        int idx0 = base + threadIdx.x * VT;
        int tsum = 0;
#pragma unroll
        for (int t = 0; t < VT; t++) {
            int i = idx0 + t;
            v[t] = (i < n) ? cnt_cursor[i] : 0;
            tsum += v[t];
        }
        int incl = tsum;
        for (int off = 1; off < 64; off <<= 1) {
            int t = __shfl_up(incl, off);
            if (lane >= off) incl += t;
        }
        if (lane == 63) wsum[wid] = incl;
        __syncthreads();
        if (wid == 0) {
            int wv = (lane < 16) ? wsum[lane] : 0;
            for (int off = 1; off < 16; off <<= 1) {
                int t = __shfl_up(wv, off);
                if (lane >= off) wv += t;
            }
            if (lane < 16) wsum[lane] = wv;
        }
        __syncthreads();
        int wave_off = (wid > 0) ? wsum[wid - 1] : 0;
        int excl = incl - tsum + wave_off + s_carry;
#pragma unroll
        for (int t = 0; t < VT; t++) {
            int i = idx0 + t;
            if (i < n) {
                cnt_cursor[i] = excl;
                row_ptr[i + 1] = excl + v[t];
            }
            excl += v[t];
        }
        __syncthreads();
        if (threadIdx.x == 0) s_carry += wsum[15];
        __syncthreads();
    }
    if (threadIdx.x == 0) row_ptr[0] = 0;
}

__global__ void scatter_kernel(const int* __restrict__ src, const int* __restrict__ dst,
                               const float* __restrict__ ew, const float* __restrict__ dis,
                               int* __restrict__ cursor, int2* __restrict__ e2, int E)
{
    int e = blockIdx.x * blockDim.x + threadIdx.x;
    if (e < E) {
        int s = src[e], d = dst[e];
        int pos = atomicAdd(&cursor[d], 1);
        float nw = dis[s] * ew[e] * dis[d];
        e2[pos] = make_int2(s, __float_as_int(nw));
    }
}

// ---------------- propagation ----------------

__global__ __launch_bounds__(256) void prop1(const float* __restrict__ xv, const float* __restrict__ z,
                                             float* __restrict__ y, const int* __restrict__ rp,
                                             const int2* __restrict__ e2, int n, int mode)
{
    int node = blockIdx.x * 64 + (threadIdx.x >> 2);
    if (node >= n) return;
    int g = threadIdx.x & 3;
    int e0 = rp[node], e1 = rp[node + 1];
    float acc = 0.f;
    for (int e = e0 + g; e < e1; e += 4) {
        int2 q = e2[e];
        acc += __int_as_float(q.y) * xv[q.x];
    }
    acc += __shfl_xor(acc, 1);
    acc += __shfl_xor(acc, 2);
    if (g == 0) {
        if (z) acc += z[node];
        if (mode == 1) acc = 1.0f / (1.0f + expf(-acc));
        y[node] = acc;
    }
}

// wide propagation: wave per node; lane = (edge_sub, col4); float4 gathers, 4x edge unroll.
template<int C4, int EPW, bool HASZ, bool RELU>
__global__ __launch_bounds__(256) void propw(const float* __restrict__ X, int xstr,
                                             const float* __restrict__ Z, int zstr,
                                             float* __restrict__ Y, int ystr,
                                             const int* __restrict__ rp,
                                             const int2* __restrict__ e2, int n)
{
    int node = blockIdx.x * 4 + (threadIdx.x >> 6);
    if (node >= n) return;
    int lane = threadIdx.x & 63;
    int c4 = lane % C4;
    int e_sub = lane / C4;
    bool active = (lane < C4 * EPW);
    int e0 = rp[node], e1 = rp[node + 1];
    float ax = 0.f, ay = 0.f, az = 0.f, aw = 0.f;
    for (int base = e0; base < e1; base += EPW * 4) {
        int sv[4]; float wv[4];
#pragma unroll
        for (int u = 0; u < 4; u++) {
            int eid = base + u * EPW + e_sub;
            bool ok = active && (eid < e1);
            int2 q = ok ? e2[eid] : make_int2(0, 0);
            sv[u] = q.x;
            wv[u] = __int_as_float(q.y);
        }
        float4 xq[4];
#pragma unroll
        for (int u = 0; u < 4; u++)
            xq[u] = *(const float4*)(X + (size_t)sv[u] * xstr + 4 * c4);
#pragma unroll
        for (int u = 0; u < 4; u++) {
            ax += wv[u] * xq[u].x; ay += wv[u] * xq[u].y;
            az += wv[u] * xq[u].z; aw += wv[u] * xq[u].w;
        }
    }
    float ox = ax, oy = ay, oz = az, ow = aw;
#pragma unroll
    for (int g = 1; g < EPW; g++) {
        int sl = c4 + g * C4;
        ax += __shfl(ox, sl); ay += __shfl(oy, sl);
        az += __shfl(oz, sl); aw += __shfl(ow, sl);
    }
    if (lane < C4) {
        if (HASZ) {
            float4 zq = *(const float4*)(Z + (size_t)node * zstr + 4 * c4);
            ax += zq.x; ay += zq.y; az += zq.z; aw += zq.w;
        }
        if (RELU) {
            ax = fmaxf(ax, 0.f); ay = fmaxf(ay, 0.f);
            az = fmaxf(az, 0.f); aw = fmaxf(aw, 0.f);
        }
        float4 o = { ax, ay, az, aw };
        *(float4*)(Y + (size_t)node * ystr + 4 * c4) = o;
    }
}

// ---------------- fp32 GEMM (small/odd shapes; R3-proven config) ----------------

__global__ __launch_bounds__(256) void gemm2(
    const float* __restrict__ X, int x_sn, int x_sk,
    const float* __restrict__ W, int w_sk, int w_sc,
    const float* __restrict__ bias,
    float* __restrict__ out, int o_sn, int o_sc,
    int M, int K, int NC, int flags, int bias_cols)
{
    __shared__ float Xs[BK][BM + 4];
    __shared__ float Ws[BK][BN];
    int tid = threadIdx.x;
    int bm = blockIdx.x * BM;
    int bn = blockIdx.y * BN;
    int tx = tid & 15, ty = tid >> 4;
    float acc[8][4] = {};
    int xk = tid & 15, xm = tid >> 4;
    int wc = tid & 63, wk4 = tid >> 6;
    int vr = tid >> 2;
    int vc = (tid & 3) * 4;
    int wvk = tid >> 4;
    int wvc = (tid & 15) * 4;
    bool xvec = (x_sk == 1) && ((x_sn & 3) == 0) && (bm + BM <= M);
    bool wvec = (w_sc == 1) && ((w_sk & 3) == 0) && (bn + BN <= NC);
    for (int k0 = 0; k0 < K; k0 += BK) {
        bool fullk = (k0 + BK <= K);
        if (xvec && fullk) {
#pragma unroll
            for (int h = 0; h < 2; h++) {
                int m = vr + 64 * h;
                const float4 q = *(const float4*)(X + (size_t)(bm + m) * x_sn + k0 + vc);
                Xs[vc + 0][m] = q.x; Xs[vc + 1][m] = q.y;
                Xs[vc + 2][m] = q.z; Xs[vc + 3][m] = q.w;
            }
        } else {
#pragma unroll
            for (int r = 0; r < 8; r++) {
                int m = xm + 16 * r;
                int gm = bm + m, gk = k0 + xk;
                Xs[xk][m] = (gm < M && gk < K) ? X[(size_t)gm * x_sn + (size_t)gk * x_sk] : 0.f;
            }
        }
        if (wvec && fullk) {
            *(float4*)&Ws[wvk][wvc] = *(const float4*)(W + (size_t)(k0 + wvk) * w_sk + bn + wvc);
        } else {
#pragma unroll
            for (int r = 0; r < 4; r++) {
                int kk = wk4 + 4 * r;
                int gk = k0 + kk, gc = bn + wc;
                Ws[kk][wc] = (gk < K && gc < NC) ? W[(size_t)gk * w_sk + (size_t)gc * w_sc] : 0.f;
            }
        }
        __syncthreads();
#pragma unroll
        for (int kk = 0; kk < BK; kk++) {
            float xv[8], wv[4];
#pragma unroll
            for (int i = 0; i < 8; i++) xv[i] = Xs[kk][ty * 8 + i];
#pragma unroll
            for (int j = 0; j < 4; j++) wv[j] = Ws[kk][tx * 4 + j];
#pragma unroll
            for (int i = 0; i < 8; i++)
#pragma unroll
                for (int j = 0; j < 4; j++)
                    acc[i][j] += xv[i] * wv[j];
        }
        __syncthreads();
    }
    bool ovec = (o_sc == 1) && ((o_sn & 3) == 0) && (bn + tx * 4 + 3 < NC);
#pragma unroll
    for (int i = 0; i < 8; i++) {
        int gm = bm + ty * 8 + i;
        if (gm >= M) continue;
        if (ovec) {
            float* op = out + (size_t)gm * o_sn + bn + tx * 4;
            float4 v = { acc[i][0], acc[i][1], acc[i][2], acc[i][3] };
            if (flags & GF_ACC) {
                float4 o = *(const float4*)op;
                v.x += o.x; v.y += o.y; v.z += o.z; v.w += o.w;
            }
            if (flags & GF_BIAS) {
#pragma unroll
                for (int j = 0; j < 4; j++) {
                    int gc = bn + tx * 4 + j;
                    if (gc < bias_cols) (&v.x)[j] += bias[gc];
                }
            }
            if (flags & GF_RELU) {
                v.x = fmaxf(v.x, 0.f); v.y = fmaxf(v.y, 0.f);
                v.z = fmaxf(v.z, 0.f); v.w = fmaxf(v.w, 0.f);
            }
            *(float4*)op = v;
        } else {
#pragma unroll
            for (int j = 0; j < 4; j++) {
                int gc = bn + tx * 4 + j;
                if (gc >= NC) continue;
                size_t oi = (size_t)gm * o_sn + (size_t)gc * o_sc;
                float v = acc[i][j];
                if (flags & GF_ACC)  v += out[oi];
                if ((flags & GF_BIAS) && gc < bias_cols) v += bias[gc];
                if (flags & GF_RELU) v = fmaxf(v, 0.f);
                out[oi] = v;
            }
        }
    }
}

// ---------------- 3-term bf16 split (hi + mid + lo; residual ~2^-27) ----------------

__device__ __forceinline__ void bf16_split3(float v, unsigned short* h,
                                            unsigned short* m, unsigned short* l)
{
    unsigned u = __float_as_uint(v);
    unsigned uh = (u + 0x8000u) & 0xFFFF0000u;
    float fh = __uint_as_float(uh);
    float r1 = v - fh;
    unsigned u1 = __float_as_uint(r1);
    unsigned um = (u1 + 0x8000u) & 0xFFFF0000u;
    float fm = __uint_as_float(um);
    float r2 = r1 - fm;
    unsigned ul = (__float_as_uint(r2) + 0x8000u) & 0xFFFF0000u;
    *h = (unsigned short)(uh >> 16);
    *m = (unsigned short)(um >> 16);
    *l = (unsigned short)(ul >> 16);
}

// W [hops, Cin, Cout] -> WT h/m/l [NCpad, Kpad], n = cout, k = hop_slot*slot + c
__global__ void splitW_stack(const float* __restrict__ Wsrc, int hop0, int H,
                             int Cin, int Cout, int slot, int Kpad, int NCpad,
                             unsigned short* __restrict__ hi, unsigned short* __restrict__ mi,
                             unsigned short* __restrict__ lo)
{
    int t = blockIdx.x * blockDim.x + threadIdx.x;
    if (t >= NCpad * Kpad) return;
    int k = t % Kpad, n = t / Kpad;
    int j = k / slot, c = k % slot;
    float v = (n < Cout && j < H && c < Cin)
        ? Wsrc[((size_t)(hop0 + j) * Cin + c) * Cout + n] : 0.f;
    unsigned short h8, m8, l8;
    bf16_split3(v, &h8, &m8, &l8);
    hi[t] = h8; mi[t] = m8; lo[t] = l8;
}

// W4 [21, 200, 80] -> WT h/m/l [NCpad, Kpad], n = (hop-k_lo)*80 + co, k = cin
__global__ void splitW_horner(const float* __restrict__ W4, int k_lo, int nb,
                              int Kpad, int NCpad,
                              unsigned short* __restrict__ hi, unsigned short* __restrict__ mi,
                              unsigned short* __restrict__ lo)
{
    int t = blockIdx.x * blockDim.x + threadIdx.x;
    if (t >= NCpad * Kpad) return;
    int k = t % Kpad, n = t / Kpad;
    float v = 0.f;
    if (k < 200 && n < nb * 80) {
        int hop = k_lo + n / 80, co = n % 80;
        v = W4[(size_t)hop * 16000 + (size_t)k * 80 + co];
    }
    unsigned short h8, m8, l8;
    bf16_split3(v, &h8, &m8, &l8);
    hi[t] = h8; mi[t] = m8; lo[t] = l8;
}

// ---------------- MFMA GEMM (3-term split, 6 products, fp32 acc) ----------------
// out[m, c] (+)= X[m, :K] * W ; W pre-split/transposed [NCpad, Kpad].
// Tile 128x64, 4 waves (32 rows each), per wave 2 m-tiles x 4 n-tiles of 16x16x32.
#define MFM 128
#define MFN 64
#define LSTR 40

__global__ __launch_bounds__(256) void gemm_mfma(
    const float* __restrict__ X, int x_sn,
    const unsigned short* __restrict__ Whi, const unsigned short* __restrict__ Wmi,
    const unsigned short* __restrict__ Wlo, int Kpad,
    const float* __restrict__ bias,
    float* __restrict__ out, int o_sn,
    int M, int K, int NC, int flags, int bias_cols)
{
    __shared__ unsigned short Ah[MFM][LSTR];
    __shared__ unsigned short Am[MFM][LSTR];
    __shared__ unsigned short Al[MFM][LSTR];
    __shared__ unsigned short Bh[MFN][LSTR];
    __shared__ unsigned short Bm[MFN][LSTR];
    __shared__ unsigned short Bl[MFN][LSTR];
    int tid = threadIdx.x;
    int bm = blockIdx.x * MFM;
    int bn = blockIdx.y * MFN;
    int w = tid >> 6, lane = tid & 63;
    int q = lane >> 4, r = lane & 15;
    f32x4 acc[2][4];
#pragma unroll
    for (int a = 0; a < 2; a++)
#pragma unroll
        for (int b = 0; b < 4; b++)
            acc[a][b] = (f32x4){0.f, 0.f, 0.f, 0.f};
    int sm = tid >> 1;
    int skq = (tid & 1) * 16;
    int bnr = tid >> 2;
    int bkq = (tid & 3) * 8;
    const float* xbase = X + (size_t)(bm + sm) * x_sn + skq;
    int ksteps = (K + 31) / 32;
    for (int ks = 0; ks < ksteps; ks++) {
        int k0 = ks * 32;
        // stage X -> 3-term bf16 split (unguarded reads: tail garbage is finite and
        // multiplied by zero-padded W rows or discarded by the guarded store)
#pragma unroll
        for (int h = 0; h < 2; h++) {
            float4 f0 = *(const float4*)(xbase + k0 + 8 * h);
            float4 f1 = *(const float4*)(xbase + k0 + 8 * h + 4);
            float vf[8] = { f0.x, f0.y, f0.z, f0.w, f1.x, f1.y, f1.z, f1.w };
            u16x8 vh, vm, vl;
#pragma unroll
            for (int j = 0; j < 8; j++) {
                unsigned short hh, mm, ll;
                bf16_split3(vf[j], &hh, &mm, &ll);
                vh[j] = hh; vm[j] = mm; vl[j] = ll;
            }
            *(u16x8*)&Ah[sm][skq + 8 * h] = vh;
            *(u16x8*)&Am[sm][skq + 8 * h] = vm;
            *(u16x8*)&Al[sm][skq + 8 * h] = vl;
        }
        size_t wo = (size_t)(bn + bnr) * Kpad + k0 + bkq;
        *(u16x8*)&Bh[bnr][bkq] = *(const u16x8*)(Whi + wo);
        *(u16x8*)&Bm[bnr][bkq] = *(const u16x8*)(Wmi + wo);
        *(u16x8*)&Bl[bnr][bkq] = *(const u16x8*)(Wlo + wo);
        __syncthreads();
#pragma unroll
        for (int mt = 0; mt < 2; mt++) {
            int arow = w * 32 + mt * 16 + r;
            bf16x8 ah = *(const bf16x8*)&Ah[arow][q * 8];
            bf16x8 am = *(const bf16x8*)&Am[arow][q * 8];
            bf16x8 al = *(const bf16x8*)&Al[arow][q * 8];
#pragma unroll
            for (int nt = 0; nt < 4; nt++) {
                bf16x8 bh = *(const bf16x8*)&Bh[nt * 16 + r][q * 8];
                bf16x8 bm2 = *(const bf16x8*)&Bm[nt * 16 + r][q * 8];
                bf16x8 bl = *(const bf16x8*)&Bl[nt * 16 + r][q * 8];
                // ascending magnitude: lh, hl, mm, mh, hm, hh
                acc[mt][nt] = __builtin_amdgcn_mfma_f32_16x16x32_bf16(al, bh, acc[mt][nt], 0, 0, 0);
                acc[mt][nt] = __builtin_amdgcn_mfma_f32_16x16x32_bf16(ah, bl, acc[mt][nt], 0, 0, 0);
                acc[mt][nt] = __builtin_amdgcn_mfma_f32_16x16x32_bf16(am, bm2, acc[mt][nt], 0, 0, 0);
                acc[mt][nt] = __builtin_amdgcn_mfma_f32_16x16x32_bf16(am, bh, acc[mt][nt], 0, 0, 0);
                acc[mt][nt] = __builtin_amdgcn_mfma_f32_16x16x32_bf16(ah, bm2, acc[mt][nt], 0, 0, 0);
                acc[mt][nt] = __builtin_amdgcn_mfma_f32_16x16x32_bf16(ah, bh, acc[mt][nt], 0, 0, 0);
            }
        }
        __syncthreads();
    }
#pragma unroll
    for (int mt = 0; mt < 2; mt++) {
#pragma unroll
        for (int i = 0; i < 4; i++) {
            int gm = bm + w * 32 + mt * 16 + q * 4 + i;
            if (gm >= M) continue;
#pragma unroll
            for (int nt = 0; nt < 4; nt++) {
                int gc = bn + nt * 16 + r;
                if (gc >= NC) continue;
                size_t oi = (size_t)gm * o_sn + gc;
                float v = acc[mt][nt][i];
                if (flags & GF_ACC)  v += out[oi];
                if ((flags & GF_BIAS) && gc < bias_cols) v += bias[gc];
                if (flags & GF_RELU) v = fmaxf(v, 0.f);
                out[oi] = v;
            }
        }
    }
}

// ---------------- launch ----------------

extern "C" void kernel_launch(void* const* d_in, const int* in_sizes, int n_in,
                              void* d_out, int out_size, void* d_ws, size_t ws_size,
                              hipStream_t stream)
{
    const int N = 50000, E = 800000, K = 20;
    const float* x  = (const float*)d_in[0];
    const int*   ei = (const int*)d_in[1];
    const float* ew = (const float*)d_in[2];
    const float* Wl[5]; const float* bl[5];
    for (int l = 0; l < 5; l++) { Wl[l] = (const float*)d_in[3 + 2 * l]; bl[l] = (const float*)d_in[4 + 2 * l]; }
    const int* src = ei;
    const int* dst = ei + E;
    (void)in_sizes; (void)n_in; (void)out_size;

    uintptr_t base = (uintptr_t)d_ws;
    uintptr_t cur = base;
    auto alloc = [&](size_t bytes) -> char* {
        uintptr_t q = (cur + 255) & ~(uintptr_t)255;
        cur = q + bytes;
        return (char*)q;
    };
    float* deg    = (float*)alloc((size_t)N * 4);
    float* dis    = (float*)alloc((size_t)N * 4);
    int*   rowptr = (int*)alloc((size_t)(N + 1) * 4);
    int*   cursor = (int*)alloc((size_t)N * 4);
    int2*  e2     = (int2*)alloc((size_t)E * 8);
    float* Zb     = (float*)alloc((size_t)(K + 1) * N * 4);  // [21, N] hop-major
    float* ya     = (float*)alloc((size_t)N * 4);
    float* yb     = (float*)alloc((size_t)N * 4);
    float* h1     = (float*)alloc((size_t)N * 64 * 4);   // stride 64 (padded, gathered)
    float* h2     = (float*)alloc((size_t)N * 100 * 4);
    float* h3     = (float*)alloc((size_t)N * 200 * 4);
    float* h4     = (float*)alloc((size_t)N * 80 * 4);
    float* Ra     = (float*)alloc((size_t)N * 96 * 4);   // stride 96 (padded, gathered)
    float* Rb     = (float*)alloc((size_t)N * 96 * 4);

    // adaptive hop-batch arena; WT planes AFTER the arena so MFMA's X tail
    // over-reads from Sb land in allocated memory.
    size_t used = (size_t)(cur - base);
    size_t reserve = (size_t)8 << 20;   // 6 MB WT planes + slack
    size_t avail = (ws_size > used + reserve) ? (ws_size - used - reserve) : 0;
    size_t cap = (size_t)N * 2000 * 4;  // 400 MB = full 20-slot C=100 stack
    size_t arena_bytes = avail < cap ? avail : cap;
    float* Sb = (float*)alloc(arena_bytes);
    unsigned short* WThi = (unsigned short*)alloc((size_t)2 << 20);
    unsigned short* WTmi = (unsigned short*)alloc((size_t)2 << 20);
    unsigned short* WTlo = (unsigned short*)alloc((size_t)2 << 20);
    auto clampH = [&](int slotw, int hi) {
        long h = (long)(arena_bytes / ((size_t)N * slotw * 4));
        if (h < 1) h = 1;
        if (h > hi) h = hi;
        return (int)h;
    };
    const int H2s = clampH(64, K);
    const int H3s = clampH(100, K);
    const int B4s = clampH(80, K + 1);
    const int rowstr2 = H2s * 64;
    const int rowstr3 = H3s * 100;
    const int rowstr4 = B4s * 80;

    // ---- CSR build
    hipMemsetAsync(deg, 0, (size_t)N * 4, stream);
    hipMemsetAsync(cursor, 0, (size_t)N * 4, stream);
    deg_count_kernel<<<(E + 255) / 256, 256, 0, stream>>>(src, dst, ew, deg, cursor, E);
    dis_kernel<<<(N + 255) / 256, 256, 0, stream>>>(deg, dis, N);
    scan_kernel<<<1, 1024, 0, stream>>>(cursor, rowptr, N);
    scatter_kernel<<<(E + 255) / 256, 256, 0, stream>>>(src, dst, ew, dis, cursor, e2, E);

    const int PB = (N + 63) / 64;
    const int WB = (N + 3) / 4;
    const int GMX = (N + BM - 1) / BM;     // fp32 gemm2 m-blocks
    const int MGX = (N + MFM - 1) / MFM;   // mfma m-blocks
    auto gyf = [](int NC) { return (NC + BN - 1) / BN; };  // BUGFIX R6: grid-y from NC

    // ---- Layer 1 (1 -> 60): width-1 chain into Zb, one fp32 GEMM K=21
    hipMemcpyAsync(Zb, x, (size_t)N * 4, hipMemcpyDeviceToDevice, stream);
    for (int k = 1; k <= K; k++)
        prop1<<<PB, 256, 0, stream>>>(Zb + (size_t)(k - 1) * N, nullptr, Zb + (size_t)k * N,
                                      rowptr, e2, N, 0);
    gemm2<<<dim3(GMX, gyf(60)), 256, 0, stream>>>(Zb, 1, N, Wl[0], 60, 1, bl[0],
                                                  h1, 64, 1, N, K + 1, 60, GF_BIAS | GF_RELU, 60);

    // ---- Layer 2 (60 -> 100): hop-batched stack (64-wide slots) + MFMA long-K GEMM
    gemm2<<<dim3(GMX, gyf(100)), 256, 0, stream>>>(h1, 64, 1, Wl[1], 100, 1, bl[1],
                                                   h2, 100, 1, N, 60, 100, GF_BIAS, 100);
    {
        int done = 0;
        const float* prevp = h1; int prevstr = 64;
        while (done < K) {
            int H = (K - done < H2s) ? (K - done) : H2s;
            for (int j = 0; j < H; j++) {
                float* dstp = Sb + j * 64;
                propw<15, 4, false, false><<<WB, 256, 0, stream>>>(prevp, prevstr, nullptr, 0,
                    dstp, rowstr2, rowptr, e2, N);
                prevp = dstp; prevstr = rowstr2;
            }
            int Kg = H * 64;                       // multiple of 32
            int NCp = 128;
            int tot = NCp * Kg;
            splitW_stack<<<(tot + 255) / 256, 256, 0, stream>>>(Wl[1], 1 + done, H, 60, 100, 64,
                                                               Kg, NCp, WThi, WTmi, WTlo);
            bool last = (done + H == K);
            gemm_mfma<<<dim3(MGX, NCp / 64), 256, 0, stream>>>(Sb, rowstr2, WThi, WTmi, WTlo, Kg,
                nullptr, h2, 100, N, Kg, 100, GF_ACC | (last ? GF_RELU : 0), 0);
            done += H;
        }
    }

    // ---- Layer 3 (100 -> 200): hop-batched stack + MFMA long-K GEMM
    gemm2<<<dim3(GMX, gyf(200)), 256, 0, stream>>>(h2, 100, 1, Wl[2], 200, 1, bl[2],
                                                   h3, 200, 1, N, 100, 200, GF_BIAS, 200);
    {
        int done = 0;
        const float* prevp = h2; int prevstr = 100;
        while (done < K) {
            int H = (K - done < H3s) ? (K - done) : H3s;
            for (int j = 0; j < H; j++) {
                float* dstp = Sb + j * 100;
                propw<25, 2, false, false><<<WB, 256, 0, stream>>>(prevp, prevstr, nullptr, 0,
                    dstp, rowstr3, rowptr, e2, N);
                prevp = dstp; prevstr = rowstr3;
            }
            int Kg = H * 100;
            int Kp = (Kg + 31) & ~31;
            int NCp = 256;
            int tot = NCp * Kp;
            splitW_stack<<<(tot + 255) / 256, 256, 0, stream>>>(Wl[2], 1 + done, H, 100, 200, 100,
                                                               Kp, NCp, WThi, WTmi, WTlo);
            bool last = (done + H == K);
            gemm_mfma<<<dim3(MGX, NCp / 64), 256, 0, stream>>>(Sb, rowstr3, WThi, WTmi, WTlo, Kp,
                nullptr, h3, 200, N, Kg, 200, GF_ACC | (last ? GF_RELU : 0), 0);
            done += H;
        }
    }

    // ---- Layer 4 (200 -> 80): batched Z pre-GEMM (MFMA) + Horner width-80
    {
        const float* curR = nullptr; int curstr = 0;
        int k_hi = K;
        while (k_hi >= 0) {
            int k_lo = k_hi - B4s + 1; if (k_lo < 0) k_lo = 0;
            int nb = k_hi - k_lo + 1;
            int NCp = ((nb * 80 + 63) / 64) * 64;
            int tot = NCp * 224;
            splitW_horner<<<(tot + 255) / 256, 256, 0, stream>>>(Wl[3], k_lo, nb, 224, NCp,
                                                                 WThi, WTmi, WTlo);
            gemm_mfma<<<dim3(MGX, NCp / 64), 256, 0, stream>>>(h3, 200, WThi, WTmi, WTlo, 224,
                bl[3], Sb, rowstr4, N, 200, nb * 80, (k_lo == 0) ? GF_BIAS : 0, 80);
            int kstart;
            if (k_hi == K) { curR = Sb + (size_t)(K - k_lo) * 80; curstr = rowstr4; kstart = K - 1; }
            else kstart = k_hi;
            for (int k = kstart; k >= k_lo; k--) {
                const float* Zp = Sb + (size_t)(k - k_lo) * 80;
                if (k == 0) {
                    propw<20, 3, true, true><<<WB, 256, 0, stream>>>(curR, curstr, Zp, rowstr4,
                        h4, 80, rowptr, e2, N);
                } else {
                    float* o = (k & 1) ? Ra : Rb;
                    propw<20, 3, true, false><<<WB, 256, 0, stream>>>(curR, curstr, Zp, rowstr4,
                        o, 96, rowptr, e2, N);
                    curR = o; curstr = 96;
                }
            }
            k_hi = k_lo - 1;
        }
    }

    // ---- Layer 5 (80 -> 1): Z5 [21, N] hop-major, Horner width-1 with sigmoid
    gemm2<<<dim3(GMX, gyf(21)), 256, 0, stream>>>(h4, 80, 1, Wl[4], 1, 80, bl[4],
                                                  Zb, 1, N, N, 80, K + 1, GF_BIAS, 1);
    const float* cur5 = Zb + (size_t)K * N;
    float* outp = (float*)d_out;
    for (int k = K - 1; k >= 0; k--) {
        float* o = (k == 0) ? outp : ((k & 1) ? ya : yb);
        prop1<<<PB, 256, 0, stream>>>(cur5, Zb + (size_t)k * N, o,
                                      rowptr, e2, N, (k == 0) ? 1 : 0);
        cur5 = o;
    }
}

// Round 8
// 4258.413 us; speedup vs baseline: 1.2599x; 1.0318x over previous
//
#include <hip/hip_runtime.h>
#include <stdint.h>

#define GF_ACC   1
#define GF_BIAS  2
#define GF_RELU  8

#define BM 128
#define BN 64
#define BK 16

typedef short bf16x8 __attribute__((ext_vector_type(8)));
typedef float f32x4 __attribute__((ext_vector_type(4)));
typedef unsigned short u16x8 __attribute__((ext_vector_type(8)));

// ---------------- CSR build ----------------

__global__ void deg_count_kernel(const int* __restrict__ src, const int* __restrict__ dst,
                                 const float* __restrict__ ew,
                                 float* __restrict__ deg, int* __restrict__ cnt, int E)
{
    int e = blockIdx.x * blockDim.x + threadIdx.x;
    if (e < E) {
        int d = dst[e];
        atomicAdd(&deg[d], ew[e]);
        atomicAdd(&cnt[d], 1);
    }
}

__global__ void dis_kernel(const float* __restrict__ deg, float* __restrict__ dis, int n)
{
    int i = blockIdx.x * blockDim.x + threadIdx.x;
    if (i < n) {
        float d = deg[i];
        dis[i] = (d > 0.f) ? (1.0f / sqrtf(d)) : 0.f;
    }
}

__global__ __launch_bounds__(1024) void scan_kernel(int* __restrict__ cnt_cursor,
                                                    int* __restrict__ row_ptr, int n)
{
    __shared__ int wsum[16];
    __shared__ int s_carry;
    if (threadIdx.x == 0) s_carry = 0;
    __syncthreads();
    const int VT = 8;
    const int CHUNK = 1024 * VT;
    int lane = threadIdx.x & 63;
    int wid = threadIdx.x >> 6;
    for (int base = 0; base < n; base += CHUNK) {
        int v[VT];
        int idx0 = base + threadIdx.x * VT;
        int tsum = 0;
#pragma unroll
        for (int t = 0; t < VT; t++) {
            int i = idx0 + t;
            v[t] = (i < n) ? cnt_cursor[i] : 0;
            tsum += v[t];
        }
        int incl = tsum;
        for (int off = 1; off < 64; off <<= 1) {
            int t = __shfl_up(incl, off);
            if (lane >= off) incl += t;
        }
        if (lane == 63) wsum[wid] = incl;
        __syncthreads();
        if (wid == 0) {
            int wv = (lane < 16) ? wsum[lane] : 0;
            for (int off = 1; off < 16; off <<= 1) {
                int t = __shfl_up(wv, off);
                if (lane >= off) wv += t;
            }
            if (lane < 16) wsum[lane] = wv;
        }
        __syncthreads();
        int wave_off = (wid > 0) ? wsum[wid - 1] : 0;
        int excl = incl - tsum + wave_off + s_carry;
#pragma unroll
        for (int t = 0; t < VT; t++) {
            int i = idx0 + t;
            if (i < n) {
                cnt_cursor[i] = excl;
                row_ptr[i + 1] = excl + v[t];
            }
            excl += v[t];
        }
        __syncthreads();
        if (threadIdx.x == 0) s_carry += wsum[15];
        __syncthreads();
    }
    if (threadIdx.x == 0) row_ptr[0] = 0;
}

__global__ void scatter_kernel(const int* __restrict__ src, const int* __restrict__ dst,
                               const float* __restrict__ ew, const float* __restrict__ dis,
                               int* __restrict__ cursor, int2* __restrict__ e2, int E)
{
    int e = blockIdx.x * blockDim.x + threadIdx.x;
    if (e < E) {
        int s = src[e], d = dst[e];
        int pos = atomicAdd(&cursor[d], 1);
        float nw = dis[s] * ew[e] * dis[d];
        e2[pos] = make_int2(s, __float_as_int(nw));
    }
}

// ---------------- propagation ----------------

__global__ __launch_bounds__(256) void prop1(const float* __restrict__ xv, const float* __restrict__ z,
                                             float* __restrict__ y, const int* __restrict__ rp,
                                             const int2* __restrict__ e2, int n, int mode)
{
    int node = blockIdx.x * 64 + (threadIdx.x >> 2);
    if (node >= n) return;
    int g = threadIdx.x & 3;
    int e0 = rp[node], e1 = rp[node + 1];
    float acc = 0.f;
    int e = e0 + g;
    for (; e + 4 < e1; e += 8) {
        int2 qa = e2[e];
        int2 qb = e2[e + 4];
        acc += __int_as_float(qa.y) * xv[qa.x];
        acc += __int_as_float(qb.y) * xv[qb.x];
    }
    if (e < e1) {
        int2 q = e2[e];
        acc += __int_as_float(q.y) * xv[q.x];
    }
    acc += __shfl_xor(acc, 1);
    acc += __shfl_xor(acc, 2);
    if (g == 0) {
        if (z) acc += z[node];
        if (mode == 1) acc = 1.0f / (1.0f + expf(-acc));
        y[node] = acc;
    }
}

// wide propagation: wave per node; lane = (edge_sub, col4); float4 gathers, 8x edge unroll.
template<int C4, int EPW, bool HASZ, bool RELU>
__global__ __launch_bounds__(256) void propw(const float* __restrict__ X, int xstr,
                                             const float* __restrict__ Z, int zstr,
                                             float* __restrict__ Y, int ystr,
                                             const int* __restrict__ rp,
                                             const int2* __restrict__ e2, int n)
{
    int node = blockIdx.x * 4 + (threadIdx.x >> 6);
    if (node >= n) return;
    int lane = threadIdx.x & 63;
    int c4 = lane % C4;
    int e_sub = lane / C4;
    bool active = (lane < C4 * EPW);
    int e0 = rp[node], e1 = rp[node + 1];
    float ax = 0.f, ay = 0.f, az = 0.f, aw = 0.f;
    for (int base = e0; base < e1; base += EPW * 8) {
        int sv[8]; float wv[8];
#pragma unroll
        for (int u = 0; u < 8; u++) {
            int eid = base + u * EPW + e_sub;
            bool ok = active && (eid < e1);
            int2 q = ok ? e2[eid] : make_int2(0, 0);
            sv[u] = q.x;
            wv[u] = __int_as_float(q.y);
        }
        float4 xq[8];
#pragma unroll
        for (int u = 0; u < 8; u++)
            xq[u] = *(const float4*)(X + (size_t)sv[u] * xstr + 4 * c4);
#pragma unroll
        for (int u = 0; u < 8; u++) {
            ax += wv[u] * xq[u].x; ay += wv[u] * xq[u].y;
            az += wv[u] * xq[u].z; aw += wv[u] * xq[u].w;
        }
    }
    float ox = ax, oy = ay, oz = az, ow = aw;
#pragma unroll
    for (int g = 1; g < EPW; g++) {
        int sl = c4 + g * C4;
        ax += __shfl(ox, sl); ay += __shfl(oy, sl);
        az += __shfl(oz, sl); aw += __shfl(ow, sl);
    }
    if (lane < C4) {
        if (HASZ) {
            float4 zq = *(const float4*)(Z + (size_t)node * zstr + 4 * c4);
            ax += zq.x; ay += zq.y; az += zq.z; aw += zq.w;
        }
        if (RELU) {
            ax = fmaxf(ax, 0.f); ay = fmaxf(ay, 0.f);
            az = fmaxf(az, 0.f); aw = fmaxf(aw, 0.f);
        }
        float4 o = { ax, ay, az, aw };
        *(float4*)(Y + (size_t)node * ystr + 4 * c4) = o;
    }
}

// ---------------- fp32 GEMM (small/odd shapes; R3-proven config) ----------------

__global__ __launch_bounds__(256) void gemm2(
    const float* __restrict__ X, int x_sn, int x_sk,
    const float* __restrict__ W, int w_sk, int w_sc,
    const float* __restrict__ bias,
    float* __restrict__ out, int o_sn, int o_sc,
    int M, int K, int NC, int flags, int bias_cols)
{
    __shared__ float Xs[BK][BM + 4];
    __shared__ float Ws[BK][BN];
    int tid = threadIdx.x;
    int bm = blockIdx.x * BM;
    int bn = blockIdx.y * BN;
    int tx = tid & 15, ty = tid >> 4;
    float acc[8][4] = {};
    int xk = tid & 15, xm = tid >> 4;
    int wc = tid & 63, wk4 = tid >> 6;
    int vr = tid >> 2;
    int vc = (tid & 3) * 4;
    int wvk = tid >> 4;
    int wvc = (tid & 15) * 4;
    bool xvec = (x_sk == 1) && ((x_sn & 3) == 0) && (bm + BM <= M);
    bool wvec = (w_sc == 1) && ((w_sk & 3) == 0) && (bn + BN <= NC);
    for (int k0 = 0; k0 < K; k0 += BK) {
        bool fullk = (k0 + BK <= K);
        if (xvec && fullk) {
#pragma unroll
            for (int h = 0; h < 2; h++) {
                int m = vr + 64 * h;
                const float4 q = *(const float4*)(X + (size_t)(bm + m) * x_sn + k0 + vc);
                Xs[vc + 0][m] = q.x; Xs[vc + 1][m] = q.y;
                Xs[vc + 2][m] = q.z; Xs[vc + 3][m] = q.w;
            }
        } else {
#pragma unroll
            for (int r = 0; r < 8; r++) {
                int m = xm + 16 * r;
                int gm = bm + m, gk = k0 + xk;
                Xs[xk][m] = (gm < M && gk < K) ? X[(size_t)gm * x_sn + (size_t)gk * x_sk] : 0.f;
            }
        }
        if (wvec && fullk) {
            *(float4*)&Ws[wvk][wvc] = *(const float4*)(W + (size_t)(k0 + wvk) * w_sk + bn + wvc);
        } else {
#pragma unroll
            for (int r = 0; r < 4; r++) {
                int kk = wk4 + 4 * r;
                int gk = k0 + kk, gc = bn + wc;
                Ws[kk][wc] = (gk < K && gc < NC) ? W[(size_t)gk * w_sk + (size_t)gc * w_sc] : 0.f;
            }
        }
        __syncthreads();
#pragma unroll
        for (int kk = 0; kk < BK; kk++) {
            float xv[8], wv[4];
#pragma unroll
            for (int i = 0; i < 8; i++) xv[i] = Xs[kk][ty * 8 + i];
#pragma unroll
            for (int j = 0; j < 4; j++) wv[j] = Ws[kk][tx * 4 + j];
#pragma unroll
            for (int i = 0; i < 8; i++)
#pragma unroll
                for (int j = 0; j < 4; j++)
                    acc[i][j] += xv[i] * wv[j];
        }
        __syncthreads();
    }
    bool ovec = (o_sc == 1) && ((o_sn & 3) == 0) && (bn + tx * 4 + 3 < NC);
#pragma unroll
    for (int i = 0; i < 8; i++) {
        int gm = bm + ty * 8 + i;
        if (gm >= M) continue;
        if (ovec) {
            float* op = out + (size_t)gm * o_sn + bn + tx * 4;
            float4 v = { acc[i][0], acc[i][1], acc[i][2], acc[i][3] };
            if (flags & GF_ACC) {
                float4 o = *(const float4*)op;
                v.x += o.x; v.y += o.y; v.z += o.z; v.w += o.w;
            }
            if (flags & GF_BIAS) {
#pragma unroll
                for (int j = 0; j < 4; j++) {
                    int gc = bn + tx * 4 + j;
                    if (gc < bias_cols) (&v.x)[j] += bias[gc];
                }
            }
            if (flags & GF_RELU) {
                v.x = fmaxf(v.x, 0.f); v.y = fmaxf(v.y, 0.f);
                v.z = fmaxf(v.z, 0.f); v.w = fmaxf(v.w, 0.f);
            }
            *(float4*)op = v;
        } else {
#pragma unroll
            for (int j = 0; j < 4; j++) {
                int gc = bn + tx * 4 + j;
                if (gc >= NC) continue;
                size_t oi = (size_t)gm * o_sn + (size_t)gc * o_sc;
                float v = acc[i][j];
                if (flags & GF_ACC)  v += out[oi];
                if ((flags & GF_BIAS) && gc < bias_cols) v += bias[gc];
                if (flags & GF_RELU) v = fmaxf(v, 0.f);
                out[oi] = v;
            }
        }
    }
}

// ---------------- 3-term bf16 split (round-nearest, used for W prep) ----------------

__device__ __forceinline__ void bf16_split3(float v, unsigned short* h,
                                            unsigned short* m, unsigned short* l)
{
    unsigned u = __float_as_uint(v);
    unsigned uh = (u + 0x8000u) & 0xFFFF0000u;
    float fh = __uint_as_float(uh);
    float r1 = v - fh;
    unsigned u1 = __float_as_uint(r1);
    unsigned um = (u1 + 0x8000u) & 0xFFFF0000u;
    float fm = __uint_as_float(um);
    float r2 = r1 - fm;
    unsigned ul = (__float_as_uint(r2) + 0x8000u) & 0xFFFF0000u;
    *h = (unsigned short)(uh >> 16);
    *m = (unsigned short)(um >> 16);
    *l = (unsigned short)(ul >> 16);
}

// W [hops, Cin, Cout] -> WT h/m/l [NCpad, Kpad], n = cout, k = hop_slot*slot + c
__global__ void splitW_stack(const float* __restrict__ Wsrc, int hop0, int H,
                             int Cin, int Cout, int slot, int Kpad, int NCpad,
                             unsigned short* __restrict__ hi, unsigned short* __restrict__ mi,
                             unsigned short* __restrict__ lo)
{
    int t = blockIdx.x * blockDim.x + threadIdx.x;
    if (t >= NCpad * Kpad) return;
    int k = t % Kpad, n = t / Kpad;
    int j = k / slot, c = k % slot;
    float v = (n < Cout && j < H && c < Cin)
        ? Wsrc[((size_t)(hop0 + j) * Cin + c) * Cout + n] : 0.f;
    unsigned short h8, m8, l8;
    bf16_split3(v, &h8, &m8, &l8);
    hi[t] = h8; mi[t] = m8; lo[t] = l8;
}

// W4 [21, 200, 80] -> WT h/m/l [NCpad, Kpad], n = (hop-k_lo)*80 + co, k = cin
__global__ void splitW_horner(const float* __restrict__ W4, int k_lo, int nb,
                              int Kpad, int NCpad,
                              unsigned short* __restrict__ hi, unsigned short* __restrict__ mi,
                              unsigned short* __restrict__ lo)
{
    int t = blockIdx.x * blockDim.x + threadIdx.x;
    if (t >= NCpad * Kpad) return;
    int k = t % Kpad, n = t / Kpad;
    float v = 0.f;
    if (k < 200 && n < nb * 80) {
        int hop = k_lo + n / 80, co = n % 80;
        v = W4[(size_t)hop * 16000 + (size_t)k * 80 + co];
    }
    unsigned short h8, m8, l8;
    bf16_split3(v, &h8, &m8, &l8);
    hi[t] = h8; mi[t] = m8; lo[t] = l8;
}

// ---------------- MFMA GEMM (3-term split, 6 products, fp32 acc) ----------------
// A staged fp32 in LDS; consuming lane trunc-splits in registers (exact: 3x8 bits
// covers the full fp32 mantissa) so split-VALU co-issues with MFMA post-barrier.
#define MFM 128
#define MFN 64
#define ASTR 36
#define LSTR 40

__global__ __launch_bounds__(256) void gemm_mfma(
    const float* __restrict__ X, int x_sn,
    const unsigned short* __restrict__ Whi, const unsigned short* __restrict__ Wmi,
    const unsigned short* __restrict__ Wlo, int Kpad,
    const float* __restrict__ bias,
    float* __restrict__ out, int o_sn,
    int M, int K, int NC, int flags, int bias_cols)
{
    __shared__ float Af[MFM][ASTR];
    __shared__ unsigned short Bh[MFN][LSTR];
    __shared__ unsigned short Bm[MFN][LSTR];
    __shared__ unsigned short Bl[MFN][LSTR];
    int tid = threadIdx.x;
    int bm = blockIdx.x * MFM;
    int bn = blockIdx.y * MFN;
    int w = tid >> 6, lane = tid & 63;
    int q = lane >> 4, r = lane & 15;
    f32x4 acc[2][4];
#pragma unroll
    for (int a = 0; a < 2; a++)
#pragma unroll
        for (int b = 0; b < 4; b++)
            acc[a][b] = (f32x4){0.f, 0.f, 0.f, 0.f};
    int sm = tid >> 1;
    int skq = (tid & 1) * 16;
    int bnr = tid >> 2;
    int bkq = (tid & 3) * 8;
    const float* xbase = X + (size_t)(bm + sm) * x_sn + skq;
    int ksteps = (K + 31) / 32;
    for (int ks = 0; ks < ksteps; ks++) {
        int k0 = ks * 32;
        // stage A as raw fp32 (unguarded tail reads: garbage is finite (0xAA poison
        // pattern = small float) and multiplied by zero-padded W)
#pragma unroll
        for (int h = 0; h < 4; h++)
            *(float4*)&Af[sm][skq + 4 * h] = *(const float4*)(xbase + k0 + 4 * h);
        size_t wo = (size_t)(bn + bnr) * Kpad + k0 + bkq;
        *(u16x8*)&Bh[bnr][bkq] = *(const u16x8*)(Whi + wo);
        *(u16x8*)&Bm[bnr][bkq] = *(const u16x8*)(Wmi + wo);
        *(u16x8*)&Bl[bnr][bkq] = *(const u16x8*)(Wlo + wo);
        __syncthreads();
#pragma unroll
        for (int mt = 0; mt < 2; mt++) {
            int arow = w * 32 + mt * 16 + r;
            float4 fa = *(const float4*)&Af[arow][q * 8];
            float4 fb = *(const float4*)&Af[arow][q * 8 + 4];
            float vf[8] = { fa.x, fa.y, fa.z, fa.w, fb.x, fb.y, fb.z, fb.w };
            bf16x8 ah, am, al;
#pragma unroll
            for (int j = 0; j < 8; j++) {
                float v = vf[j];
                unsigned u = __float_as_uint(v);
                unsigned uh = u & 0xFFFF0000u;
                float r1 = v - __uint_as_float(uh);
                unsigned u1 = __float_as_uint(r1);
                unsigned um = u1 & 0xFFFF0000u;
                float r2 = r1 - __uint_as_float(um);
                ah[j] = (short)(uh >> 16);
                am[j] = (short)(um >> 16);
                al[j] = (short)(__float_as_uint(r2) >> 16);
            }
#pragma unroll
            for (int nt = 0; nt < 4; nt++) {
                bf16x8 bh = *(const bf16x8*)&Bh[nt * 16 + r][q * 8];
                bf16x8 bm2 = *(const bf16x8*)&Bm[nt * 16 + r][q * 8];
                bf16x8 bl = *(const bf16x8*)&Bl[nt * 16 + r][q * 8];
                // ascending magnitude: lh, hl, mm, mh, hm, hh
                acc[mt][nt] = __builtin_amdgcn_mfma_f32_16x16x32_bf16(al, bh, acc[mt][nt], 0, 0, 0);
                acc[mt][nt] = __builtin_amdgcn_mfma_f32_16x16x32_bf16(ah, bl, acc[mt][nt], 0, 0, 0);
                acc[mt][nt] = __builtin_amdgcn_mfma_f32_16x16x32_bf16(am, bm2, acc[mt][nt], 0, 0, 0);
                acc[mt][nt] = __builtin_amdgcn_mfma_f32_16x16x32_bf16(am, bh, acc[mt][nt], 0, 0, 0);
                acc[mt][nt] = __builtin_amdgcn_mfma_f32_16x16x32_bf16(ah, bm2, acc[mt][nt], 0, 0, 0);
                acc[mt][nt] = __builtin_amdgcn_mfma_f32_16x16x32_bf16(ah, bh, acc[mt][nt], 0, 0, 0);
            }
        }
        __syncthreads();
    }
#pragma unroll
    for (int mt = 0; mt < 2; mt++) {
#pragma unroll
        for (int i = 0; i < 4; i++) {
            int gm = bm + w * 32 + mt * 16 + q * 4 + i;
            if (gm >= M) continue;
#pragma unroll
            for (int nt = 0; nt < 4; nt++) {
                int gc = bn + nt * 16 + r;
                if (gc >= NC) continue;
                size_t oi = (size_t)gm * o_sn + gc;
                float v = acc[mt][nt][i];
                if (flags & GF_ACC)  v += out[oi];
                if ((flags & GF_BIAS) && gc < bias_cols) v += bias[gc];
                if (flags & GF_RELU) v = fmaxf(v, 0.f);
                out[oi] = v;
            }
        }
    }
}

// ---------------- launch ----------------

extern "C" void kernel_launch(void* const* d_in, const int* in_sizes, int n_in,
                              void* d_out, int out_size, void* d_ws, size_t ws_size,
                              hipStream_t stream)
{
    const int N = 50000, E = 800000, K = 20;
    const float* x  = (const float*)d_in[0];
    const int*   ei = (const int*)d_in[1];
    const float* ew = (const float*)d_in[2];
    const float* Wl[5]; const float* bl[5];
    for (int l = 0; l < 5; l++) { Wl[l] = (const float*)d_in[3 + 2 * l]; bl[l] = (const float*)d_in[4 + 2 * l]; }
    const int* src = ei;
    const int* dst = ei + E;
    (void)in_sizes; (void)n_in; (void)out_size;

    uintptr_t base = (uintptr_t)d_ws;
    uintptr_t cur = base;
    auto alloc = [&](size_t bytes) -> char* {
        uintptr_t q = (cur + 255) & ~(uintptr_t)255;
        cur = q + bytes;
        return (char*)q;
    };
    float* deg    = (float*)alloc((size_t)N * 4);
    float* dis    = (float*)alloc((size_t)N * 4);
    int*   rowptr = (int*)alloc((size_t)(N + 1) * 4);
    int*   cursor = (int*)alloc((size_t)N * 4);
    int2*  e2     = (int2*)alloc((size_t)E * 8);
    float* Zb     = (float*)alloc((size_t)(K + 1) * N * 4);  // [21, N] hop-major
    float* ya     = (float*)alloc((size_t)N * 4);
    float* yb     = (float*)alloc((size_t)N * 4);
    float* h1     = (float*)alloc((size_t)N * 64 * 4);   // stride 64 (padded, gathered)
    float* h2     = (float*)alloc((size_t)N * 100 * 4);
    float* h3     = (float*)alloc((size_t)N * 200 * 4);
    float* h4     = (float*)alloc((size_t)N * 80 * 4);
    float* Ra     = (float*)alloc((size_t)N * 96 * 4);   // stride 96 (padded, gathered)
    float* Rb     = (float*)alloc((size_t)N * 96 * 4);

    // adaptive hop-batch arena; WT planes AFTER the arena so MFMA's X tail
    // over-reads from Sb land in allocated memory.
    size_t used = (size_t)(cur - base);
    size_t reserve = (size_t)8 << 20;   // 6 MB WT planes + slack
    size_t avail = (ws_size > used + reserve) ? (ws_size - used - reserve) : 0;
    size_t cap = (size_t)N * 2000 * 4;  // 400 MB = full 20-slot C=100 stack
    size_t arena_bytes = avail < cap ? avail : cap;
    float* Sb = (float*)alloc(arena_bytes);
    unsigned short* WThi = (unsigned short*)alloc((size_t)2 << 20);
    unsigned short* WTmi = (unsigned short*)alloc((size_t)2 << 20);
    unsigned short* WTlo = (unsigned short*)alloc((size_t)2 << 20);
    auto clampH = [&](int slotw, int hi) {
        long h = (long)(arena_bytes / ((size_t)N * slotw * 4));
        if (h < 1) h = 1;
        if (h > hi) h = hi;
        return (int)h;
    };
    const int H2s = clampH(64, K);
    const int H3s = clampH(100, K);
    const int B4s = clampH(80, K + 1);
    const int rowstr2 = H2s * 64;
    const int rowstr3 = H3s * 100;
    const int rowstr4 = B4s * 80;

    // ---- CSR build
    hipMemsetAsync(deg, 0, (size_t)N * 4, stream);
    hipMemsetAsync(cursor, 0, (size_t)N * 4, stream);
    deg_count_kernel<<<(E + 255) / 256, 256, 0, stream>>>(src, dst, ew, deg, cursor, E);
    dis_kernel<<<(N + 255) / 256, 256, 0, stream>>>(deg, dis, N);
    scan_kernel<<<1, 1024, 0, stream>>>(cursor, rowptr, N);
    scatter_kernel<<<(E + 255) / 256, 256, 0, stream>>>(src, dst, ew, dis, cursor, e2, E);

    const int PB = (N + 63) / 64;
    const int WB = (N + 3) / 4;
    const int GMX = (N + BM - 1) / BM;     // fp32 gemm2 m-blocks
    const int MGX = (N + MFM - 1) / MFM;   // mfma m-blocks
    auto gyf = [](int NC) { return (NC + BN - 1) / BN; };

    // ---- Layer 1 (1 -> 60): width-1 chain into Zb, one fp32 GEMM K=21
    hipMemcpyAsync(Zb, x, (size_t)N * 4, hipMemcpyDeviceToDevice, stream);
    for (int k = 1; k <= K; k++)
        prop1<<<PB, 256, 0, stream>>>(Zb + (size_t)(k - 1) * N, nullptr, Zb + (size_t)k * N,
                                      rowptr, e2, N, 0);
    gemm2<<<dim3(GMX, gyf(60)), 256, 0, stream>>>(Zb, 1, N, Wl[0], 60, 1, bl[0],
                                                  h1, 64, 1, N, K + 1, 60, GF_BIAS | GF_RELU, 60);

    // ---- Layer 2 (60 -> 100): hop-batched stack (64-wide slots) + MFMA long-K GEMM
    gemm2<<<dim3(GMX, gyf(100)), 256, 0, stream>>>(h1, 64, 1, Wl[1], 100, 1, bl[1],
                                                   h2, 100, 1, N, 60, 100, GF_BIAS, 100);
    {
        int done = 0;
        const float* prevp = h1; int prevstr = 64;
        while (done < K) {
            int H = (K - done < H2s) ? (K - done) : H2s;
            for (int j = 0; j < H; j++) {
                float* dstp = Sb + j * 64;
                propw<15, 4, false, false><<<WB, 256, 0, stream>>>(prevp, prevstr, nullptr, 0,
                    dstp, rowstr2, rowptr, e2, N);
                prevp = dstp; prevstr = rowstr2;
            }
            int Kg = H * 64;                       // multiple of 32
            int NCp = 128;
            int tot = NCp * Kg;
            splitW_stack<<<(tot + 255) / 256, 256, 0, stream>>>(Wl[1], 1 + done, H, 60, 100, 64,
                                                               Kg, NCp, WThi, WTmi, WTlo);
            bool last = (done + H == K);
            gemm_mfma<<<dim3(MGX, NCp / 64), 256, 0, stream>>>(Sb, rowstr2, WThi, WTmi, WTlo, Kg,
                nullptr, h2, 100, N, Kg, 100, GF_ACC | (last ? GF_RELU : 0), 0);
            done += H;
        }
    }

    // ---- Layer 3 (100 -> 200): hop-batched stack + MFMA long-K GEMM
    gemm2<<<dim3(GMX, gyf(200)), 256, 0, stream>>>(h2, 100, 1, Wl[2], 200, 1, bl[2],
                                                   h3, 200, 1, N, 100, 200, GF_BIAS, 200);
    {
        int done = 0;
        const float* prevp = h2; int prevstr = 100;
        while (done < K) {
            int H = (K - done < H3s) ? (K - done) : H3s;
            for (int j = 0; j < H; j++) {
                float* dstp = Sb + j * 100;
                propw<25, 2, false, false><<<WB, 256, 0, stream>>>(prevp, prevstr, nullptr, 0,
                    dstp, rowstr3, rowptr, e2, N);
                prevp = dstp; prevstr = rowstr3;
            }
            int Kg = H * 100;
            int Kp = (Kg + 31) & ~31;
            int NCp = 256;
            int tot = NCp * Kp;
            splitW_stack<<<(tot + 255) / 256, 256, 0, stream>>>(Wl[2], 1 + done, H, 100, 200, 100,
                                                               Kp, NCp, WThi, WTmi, WTlo);
            bool last = (done + H == K);
            gemm_mfma<<<dim3(MGX, NCp / 64), 256, 0, stream>>>(Sb, rowstr3, WThi, WTmi, WTlo, Kp,
                nullptr, h3, 200, N, Kg, 200, GF_ACC | (last ? GF_RELU : 0), 0);
            done += H;
        }
    }

    // ---- Layer 4 (200 -> 80): batched Z pre-GEMM (MFMA) + Horner width-80
    {
        const float* curR = nullptr; int curstr = 0;
        int k_hi = K;
        while (k_hi >= 0) {
            int k_lo = k_hi - B4s + 1; if (k_lo < 0) k_lo = 0;
            int nb = k_hi - k_lo + 1;
            int NCp = ((nb * 80 + 63) / 64) * 64;
            int tot = NCp * 224;
            splitW_horner<<<(tot + 255) / 256, 256, 0, stream>>>(Wl[3], k_lo, nb, 224, NCp,
                                                                 WThi, WTmi, WTlo);
            gemm_mfma<<<dim3(MGX, NCp / 64), 256, 0, stream>>>(h3, 200, WThi, WTmi, WTlo, 224,
                bl[3], Sb, rowstr4, N, 200, nb * 80, (k_lo == 0) ? GF_BIAS : 0, 80);
            int kstart;
            if (k_hi == K) { curR = Sb + (size_t)(K - k_lo) * 80; curstr = rowstr4; kstart = K - 1; }
            else kstart = k_hi;
            for (int k = kstart; k >= k_lo; k--) {
                const float* Zp = Sb + (size_t)(k - k_lo) * 80;
                if (k == 0) {
                    propw<20, 3, true, true><<<WB, 256, 0, stream>>>(curR, curstr, Zp, rowstr4,
                        h4, 80, rowptr, e2, N);
                } else {
                    float* o = (k & 1) ? Ra : Rb;
                    propw<20, 3, true, false><<<WB, 256, 0, stream>>>(curR, curstr, Zp, rowstr4,
                        o, 96, rowptr, e2, N);
                    curR = o; curstr = 96;
                }
            }
            k_hi = k_lo - 1;
        }
    }

    // ---- Layer 5 (80 -> 1): Z5 [21, N] hop-major, Horner width-1 with sigmoid
    gemm2<<<dim3(GMX, gyf(21)), 256, 0, stream>>>(h4, 80, 1, Wl[4], 1, 80, bl[4],
                                                  Zb, 1, N, N, 80, K + 1, GF_BIAS, 1);
    const float* cur5 = Zb + (size_t)K * N;
    float* outp = (float*)d_out;
    for (int k = K - 1; k >= 0; k--) {
        float* o = (k == 0) ? outp : ((k & 1) ? ya : yb);
        prop1<<<PB, 256, 0, stream>>>(cur5, Zb + (size_t)k * N, o,
                                      rowptr, e2, N, (k == 0) ? 1 : 0);
        cur5 = o;
    }
}

// Round 9
// 4173.886 us; speedup vs baseline: 1.2855x; 1.0203x over previous
//
#include <hip/hip_runtime.h>
#include <stdint.h>

#define GF_ACC   1
#define GF_BIAS  2
#define GF_RELU  8

#define BM 128
#define BN 64
#define BK 16

typedef short bf16x8 __attribute__((ext_vector_type(8)));
typedef float f32x4 __attribute__((ext_vector_type(4)));
typedef unsigned short u16x8 __attribute__((ext_vector_type(8)));

// ---------------- CSR build ----------------

__global__ void deg_count_kernel(const int* __restrict__ src, const int* __restrict__ dst,
                                 const float* __restrict__ ew,
                                 float* __restrict__ deg, int* __restrict__ cnt, int E)
{
    int e = blockIdx.x * blockDim.x + threadIdx.x;
    if (e < E) {
        int d = dst[e];
        atomicAdd(&deg[d], ew[e]);
        atomicAdd(&cnt[d], 1);
    }
}

__global__ void dis_kernel(const float* __restrict__ deg, float* __restrict__ dis, int n)
{
    int i = blockIdx.x * blockDim.x + threadIdx.x;
    if (i < n) {
        float d = deg[i];
        dis[i] = (d > 0.f) ? (1.0f / sqrtf(d)) : 0.f;
    }
}

__global__ __launch_bounds__(1024) void scan_kernel(int* __restrict__ cnt_cursor,
                                                    int* __restrict__ row_ptr, int n)
{
    __shared__ int wsum[16];
    __shared__ int s_carry;
    if (threadIdx.x == 0) s_carry = 0;
    __syncthreads();
    const int VT = 8;
    const int CHUNK = 1024 * VT;
    int lane = threadIdx.x & 63;
    int wid = threadIdx.x >> 6;
    for (int base = 0; base < n; base += CHUNK) {
        int v[VT];
        int idx0 = base + threadIdx.x * VT;
        int tsum = 0;
#pragma unroll
        for (int t = 0; t < VT; t++) {
            int i = idx0 + t;
            v[t] = (i < n) ? cnt_cursor[i] : 0;
            tsum += v[t];
        }
        int incl = tsum;
        for (int off = 1; off < 64; off <<= 1) {
            int t = __shfl_up(incl, off);
            if (lane >= off) incl += t;
        }
        if (lane == 63) wsum[wid] = incl;
        __syncthreads();
        if (wid == 0) {
            int wv = (lane < 16) ? wsum[lane] : 0;
            for (int off = 1; off < 16; off <<= 1) {
                int t = __shfl_up(wv, off);
                if (lane >= off) wv += t;
            }
            if (lane < 16) wsum[lane] = wv;
        }
        __syncthreads();
        int wave_off = (wid > 0) ? wsum[wid - 1] : 0;
        int excl = incl - tsum + wave_off + s_carry;
#pragma unroll
        for (int t = 0; t < VT; t++) {
            int i = idx0 + t;
            if (i < n) {
                cnt_cursor[i] = excl;
                row_ptr[i + 1] = excl + v[t];
            }
            excl += v[t];
        }
        __syncthreads();
        if (threadIdx.x == 0) s_carry += wsum[15];
        __syncthreads();
    }
    if (threadIdx.x == 0) row_ptr[0] = 0;
}

__global__ void scatter_kernel(const int* __restrict__ src, const int* __restrict__ dst,
                               const float* __restrict__ ew, const float* __restrict__ dis,
                               int* __restrict__ cursor, int2* __restrict__ e2, int E)
{
    int e = blockIdx.x * blockDim.x + threadIdx.x;
    if (e < E) {
        int s = src[e], d = dst[e];
        int pos = atomicAdd(&cursor[d], 1);
        float nw = dis[s] * ew[e] * dis[d];
        e2[pos] = make_int2(s, __float_as_int(nw));
    }
}

// ---------------- propagation ----------------

__global__ __launch_bounds__(256) void prop1(const float* __restrict__ xv, const float* __restrict__ z,
                                             float* __restrict__ y, const int* __restrict__ rp,
                                             const int2* __restrict__ e2, int n, int mode)
{
    int node = blockIdx.x * 64 + (threadIdx.x >> 2);
    if (node >= n) return;
    int g = threadIdx.x & 3;
    int e0 = rp[node], e1 = rp[node + 1];
    float acc = 0.f;
    int e = e0 + g;
    for (; e + 4 < e1; e += 8) {
        int2 qa = e2[e];
        int2 qb = e2[e + 4];
        acc += __int_as_float(qa.y) * xv[qa.x];
        acc += __int_as_float(qb.y) * xv[qb.x];
    }
    if (e < e1) {
        int2 q = e2[e];
        acc += __int_as_float(q.y) * xv[q.x];
    }
    acc += __shfl_xor(acc, 1);
    acc += __shfl_xor(acc, 2);
    if (g == 0) {
        if (z) acc += z[node];
        if (mode == 1) acc = 1.0f / (1.0f + expf(-acc));
        y[node] = acc;
    }
}

// propw2: LPN lanes per node, each lane owns one float4 column group and loops the
// node's edges 8-deep (no shuffle reduce, no wasted parallel-edge slots).
template<int LPN, int C4, bool HASZ, bool RELU>
__global__ __launch_bounds__(256) void propw2(const float* __restrict__ X, int xstr,
                                              const float* __restrict__ Z, int zstr,
                                              float* __restrict__ Y, int ystr,
                                              const int* __restrict__ rp,
                                              const int2* __restrict__ e2, int n)
{
    const int NPB = 256 / LPN;
    int node = blockIdx.x * NPB + threadIdx.x / LPN;
    if (node >= n) return;
    int c4 = threadIdx.x % LPN;
    bool colok = (c4 < C4);
    int cq = colok ? c4 : 0;
    int e0 = rp[node], e1 = rp[node + 1];
    float ax = 0.f, ay = 0.f, az = 0.f, aw = 0.f;
    int e = e0;
    for (; e + 8 <= e1; e += 8) {
        int2 q[8];
#pragma unroll
        for (int u = 0; u < 8; u++) q[u] = e2[e + u];
        float4 xq[8];
#pragma unroll
        for (int u = 0; u < 8; u++)
            xq[u] = *(const float4*)(X + (size_t)q[u].x * xstr + 4 * cq);
#pragma unroll
        for (int u = 0; u < 8; u++) {
            float wv = __int_as_float(q[u].y);
            ax += wv * xq[u].x; ay += wv * xq[u].y;
            az += wv * xq[u].z; aw += wv * xq[u].w;
        }
    }
    if (e < e1) {
#pragma unroll
        for (int u = 0; u < 8; u++) {
            int eid = e + u;
            int2 q = (eid < e1) ? e2[eid] : make_int2(0, 0);
            float4 xq = *(const float4*)(X + (size_t)q.x * xstr + 4 * cq);
            float wv = __int_as_float(q.y);
            ax += wv * xq.x; ay += wv * xq.y; az += wv * xq.z; aw += wv * xq.w;
        }
    }
    if (colok) {
        if (HASZ) {
            float4 zq = *(const float4*)(Z + (size_t)node * zstr + 4 * c4);
            ax += zq.x; ay += zq.y; az += zq.z; aw += zq.w;
        }
        if (RELU) {
            ax = fmaxf(ax, 0.f); ay = fmaxf(ay, 0.f);
            az = fmaxf(az, 0.f); aw = fmaxf(aw, 0.f);
        }
        float4 o = { ax, ay, az, aw };
        *(float4*)(Y + (size_t)node * ystr + 4 * c4) = o;
    }
}

// ---------------- fp32 GEMM (L1/L5 odd shapes; R3-proven config) ----------------

__global__ __launch_bounds__(256) void gemm2(
    const float* __restrict__ X, int x_sn, int x_sk,
    const float* __restrict__ W, int w_sk, int w_sc,
    const float* __restrict__ bias,
    float* __restrict__ out, int o_sn, int o_sc,
    int M, int K, int NC, int flags, int bias_cols)
{
    __shared__ float Xs[BK][BM + 4];
    __shared__ float Ws[BK][BN];
    int tid = threadIdx.x;
    int bm = blockIdx.x * BM;
    int bn = blockIdx.y * BN;
    int tx = tid & 15, ty = tid >> 4;
    float acc[8][4] = {};
    int xk = tid & 15, xm = tid >> 4;
    int wc = tid & 63, wk4 = tid >> 6;
    int vr = tid >> 2;
    int vc = (tid & 3) * 4;
    int wvk = tid >> 4;
    int wvc = (tid & 15) * 4;
    bool xvec = (x_sk == 1) && ((x_sn & 3) == 0) && (bm + BM <= M);
    bool wvec = (w_sc == 1) && ((w_sk & 3) == 0) && (bn + BN <= NC);
    for (int k0 = 0; k0 < K; k0 += BK) {
        bool fullk = (k0 + BK <= K);
        if (xvec && fullk) {
#pragma unroll
            for (int h = 0; h < 2; h++) {
                int m = vr + 64 * h;
                const float4 q = *(const float4*)(X + (size_t)(bm + m) * x_sn + k0 + vc);
                Xs[vc + 0][m] = q.x; Xs[vc + 1][m] = q.y;
                Xs[vc + 2][m] = q.z; Xs[vc + 3][m] = q.w;
            }
        } else {
#pragma unroll
            for (int r = 0; r < 8; r++) {
                int m = xm + 16 * r;
                int gm = bm + m, gk = k0 + xk;
                Xs[xk][m] = (gm < M && gk < K) ? X[(size_t)gm * x_sn + (size_t)gk * x_sk] : 0.f;
            }
        }
        if (wvec && fullk) {
            *(float4*)&Ws[wvk][wvc] = *(const float4*)(W + (size_t)(k0 + wvk) * w_sk + bn + wvc);
        } else {
#pragma unroll
            for (int r = 0; r < 4; r++) {
                int kk = wk4 + 4 * r;
                int gk = k0 + kk, gc = bn + wc;
                Ws[kk][wc] = (gk < K && gc < NC) ? W[(size_t)gk * w_sk + (size_t)gc * w_sc] : 0.f;
            }
        }
        __syncthreads();
#pragma unroll
        for (int kk = 0; kk < BK; kk++) {
            float xv[8], wv[4];
#pragma unroll
            for (int i = 0; i < 8; i++) xv[i] = Xs[kk][ty * 8 + i];
#pragma unroll
            for (int j = 0; j < 4; j++) wv[j] = Ws[kk][tx * 4 + j];
#pragma unroll
            for (int i = 0; i < 8; i++)
#pragma unroll
                for (int j = 0; j < 4; j++)
                    acc[i][j] += xv[i] * wv[j];
        }
        __syncthreads();
    }
    bool ovec = (o_sc == 1) && ((o_sn & 3) == 0) && (bn + tx * 4 + 3 < NC);
#pragma unroll
    for (int i = 0; i < 8; i++) {
        int gm = bm + ty * 8 + i;
        if (gm >= M) continue;
        if (ovec) {
            float* op = out + (size_t)gm * o_sn + bn + tx * 4;
            float4 v = { acc[i][0], acc[i][1], acc[i][2], acc[i][3] };
            if (flags & GF_ACC) {
                float4 o = *(const float4*)op;
                v.x += o.x; v.y += o.y; v.z += o.z; v.w += o.w;
            }
            if (flags & GF_BIAS) {
#pragma unroll
                for (int j = 0; j < 4; j++) {
                    int gc = bn + tx * 4 + j;
                    if (gc < bias_cols) (&v.x)[j] += bias[gc];
                }
            }
            if (flags & GF_RELU) {
                v.x = fmaxf(v.x, 0.f); v.y = fmaxf(v.y, 0.f);
                v.z = fmaxf(v.z, 0.f); v.w = fmaxf(v.w, 0.f);
            }
            *(float4*)op = v;
        } else {
#pragma unroll
            for (int j = 0; j < 4; j++) {
                int gc = bn + tx * 4 + j;
                if (gc >= NC) continue;
                size_t oi = (size_t)gm * o_sn + (size_t)gc * o_sc;
                float v = acc[i][j];
                if (flags & GF_ACC)  v += out[oi];
                if ((flags & GF_BIAS) && gc < bias_cols) v += bias[gc];
                if (flags & GF_RELU) v = fmaxf(v, 0.f);
                out[oi] = v;
            }
        }
    }
}

// ---------------- 3-term bf16 split (round-nearest, used for W prep) ----------------

__device__ __forceinline__ void bf16_split3(float v, unsigned short* h,
                                            unsigned short* m, unsigned short* l)
{
    unsigned u = __float_as_uint(v);
    unsigned uh = (u + 0x8000u) & 0xFFFF0000u;
    float fh = __uint_as_float(uh);
    float r1 = v - fh;
    unsigned u1 = __float_as_uint(r1);
    unsigned um = (u1 + 0x8000u) & 0xFFFF0000u;
    float fm = __uint_as_float(um);
    float r2 = r1 - fm;
    unsigned ul = (__float_as_uint(r2) + 0x8000u) & 0xFFFF0000u;
    *h = (unsigned short)(uh >> 16);
    *m = (unsigned short)(um >> 16);
    *l = (unsigned short)(ul >> 16);
}

// W [hops, Cin, Cout] -> WT h/m/l [NCpad, Kpad], n = cout, k = hop_slot*slot + c
__global__ void splitW_stack(const float* __restrict__ Wsrc, int hop0, int H,
                             int Cin, int Cout, int slot, int Kpad, int NCpad,
                             unsigned short* __restrict__ hi, unsigned short* __restrict__ mi,
                             unsigned short* __restrict__ lo)
{
    int t = blockIdx.x * blockDim.x + threadIdx.x;
    if (t >= NCpad * Kpad) return;
    int k = t % Kpad, n = t / Kpad;
    int j = k / slot, c = k % slot;
    float v = (n < Cout && j < H && c < Cin)
        ? Wsrc[((size_t)(hop0 + j) * Cin + c) * Cout + n] : 0.f;
    unsigned short h8, m8, l8;
    bf16_split3(v, &h8, &m8, &l8);
    hi[t] = h8; mi[t] = m8; lo[t] = l8;
}

// W4 [21, 200, 80] -> WT h/m/l [NCpad, Kpad], n = (hop-k_lo)*80 + co, k = cin
__global__ void splitW_horner(const float* __restrict__ W4, int k_lo, int nb,
                              int Kpad, int NCpad,
                              unsigned short* __restrict__ hi, unsigned short* __restrict__ mi,
                              unsigned short* __restrict__ lo)
{
    int t = blockIdx.x * blockDim.x + threadIdx.x;
    if (t >= NCpad * Kpad) return;
    int k = t % Kpad, n = t / Kpad;
    float v = 0.f;
    if (k < 200 && n < nb * 80) {
        int hop = k_lo + n / 80, co = n % 80;
        v = W4[(size_t)hop * 16000 + (size_t)k * 80 + co];
    }
    unsigned short h8, m8, l8;
    bf16_split3(v, &h8, &m8, &l8);
    hi[t] = h8; mi[t] = m8; lo[t] = l8;
}

// ---------------- MFMA GEMM (3-term split, 6 products, fp32 acc) ----------------
#define MFM 128
#define MFN 64
#define ASTR 36
#define LSTR 40

__global__ __launch_bounds__(256) void gemm_mfma(
    const float* __restrict__ X, int x_sn,
    const unsigned short* __restrict__ Whi, const unsigned short* __restrict__ Wmi,
    const unsigned short* __restrict__ Wlo, int Kpad,
    const float* __restrict__ bias,
    float* __restrict__ out, int o_sn,
    int M, int K, int NC, int flags, int bias_cols)
{
    __shared__ float Af[MFM][ASTR];
    __shared__ unsigned short Bh[MFN][LSTR];
    __shared__ unsigned short Bm[MFN][LSTR];
    __shared__ unsigned short Bl[MFN][LSTR];
    int tid = threadIdx.x;
    int bm = blockIdx.x * MFM;
    int bn = blockIdx.y * MFN;
    int w = tid >> 6, lane = tid & 63;
    int q = lane >> 4, r = lane & 15;
    f32x4 acc[2][4];
#pragma unroll
    for (int a = 0; a < 2; a++)
#pragma unroll
        for (int b = 0; b < 4; b++)
            acc[a][b] = (f32x4){0.f, 0.f, 0.f, 0.f};
    int sm = tid >> 1;
    int skq = (tid & 1) * 16;
    int bnr = tid >> 2;
    int bkq = (tid & 3) * 8;
    const float* xbase = X + (size_t)(bm + sm) * x_sn + skq;
    int ksteps = (K + 31) / 32;
    for (int ks = 0; ks < ksteps; ks++) {
        int k0 = ks * 32;
#pragma unroll
        for (int h = 0; h < 4; h++)
            *(float4*)&Af[sm][skq + 4 * h] = *(const float4*)(xbase + k0 + 4 * h);
        size_t wo = (size_t)(bn + bnr) * Kpad + k0 + bkq;
        *(u16x8*)&Bh[bnr][bkq] = *(const u16x8*)(Whi + wo);
        *(u16x8*)&Bm[bnr][bkq] = *(const u16x8*)(Wmi + wo);
        *(u16x8*)&Bl[bnr][bkq] = *(const u16x8*)(Wlo + wo);
        __syncthreads();
#pragma unroll
        for (int mt = 0; mt < 2; mt++) {
            int arow = w * 32 + mt * 16 + r;
            float4 fa = *(const float4*)&Af[arow][q * 8];
            float4 fb = *(const float4*)&Af[arow][q * 8 + 4];
            float vf[8] = { fa.x, fa.y, fa.z, fa.w, fb.x, fb.y, fb.z, fb.w };
            bf16x8 ah, am, al;
#pragma unroll
            for (int j = 0; j < 8; j++) {
                float v = vf[j];
                unsigned u = __float_as_uint(v);
                unsigned uh = u & 0xFFFF0000u;
                float r1 = v - __uint_as_float(uh);
                unsigned u1 = __float_as_uint(r1);
                unsigned um = u1 & 0xFFFF0000u;
                float r2 = r1 - __uint_as_float(um);
                ah[j] = (short)(uh >> 16);
                am[j] = (short)(um >> 16);
                al[j] = (short)(__float_as_uint(r2) >> 16);
            }
#pragma unroll
            for (int nt = 0; nt < 4; nt++) {
                bf16x8 bh = *(const bf16x8*)&Bh[nt * 16 + r][q * 8];
                bf16x8 bm2 = *(const bf16x8*)&Bm[nt * 16 + r][q * 8];
                bf16x8 bl = *(const bf16x8*)&Bl[nt * 16 + r][q * 8];
                acc[mt][nt] = __builtin_amdgcn_mfma_f32_16x16x32_bf16(al, bh, acc[mt][nt], 0, 0, 0);
                acc[mt][nt] = __builtin_amdgcn_mfma_f32_16x16x32_bf16(ah, bl, acc[mt][nt], 0, 0, 0);
                acc[mt][nt] = __builtin_amdgcn_mfma_f32_16x16x32_bf16(am, bm2, acc[mt][nt], 0, 0, 0);
                acc[mt][nt] = __builtin_amdgcn_mfma_f32_16x16x32_bf16(am, bh, acc[mt][nt], 0, 0, 0);
                acc[mt][nt] = __builtin_amdgcn_mfma_f32_16x16x32_bf16(ah, bm2, acc[mt][nt], 0, 0, 0);
                acc[mt][nt] = __builtin_amdgcn_mfma_f32_16x16x32_bf16(ah, bh, acc[mt][nt], 0, 0, 0);
            }
        }
        __syncthreads();
    }
#pragma unroll
    for (int mt = 0; mt < 2; mt++) {
#pragma unroll
        for (int i = 0; i < 4; i++) {
            int gm = bm + w * 32 + mt * 16 + q * 4 + i;
            if (gm >= M) continue;
#pragma unroll
            for (int nt = 0; nt < 4; nt++) {
                int gc = bn + nt * 16 + r;
                if (gc >= NC) continue;
                size_t oi = (size_t)gm * o_sn + gc;
                float v = acc[mt][nt][i];
                if (flags & GF_ACC)  v += out[oi];
                if ((flags & GF_BIAS) && gc < bias_cols) v += bias[gc];
                if (flags & GF_RELU) v = fmaxf(v, 0.f);
                out[oi] = v;
            }
        }
    }
}

// ---------------- launch ----------------

extern "C" void kernel_launch(void* const* d_in, const int* in_sizes, int n_in,
                              void* d_out, int out_size, void* d_ws, size_t ws_size,
                              hipStream_t stream)
{
    const int N = 50000, E = 800000, K = 20;
    const float* x  = (const float*)d_in[0];
    const int*   ei = (const int*)d_in[1];
    const float* ew = (const float*)d_in[2];
    const float* Wl[5]; const float* bl[5];
    for (int l = 0; l < 5; l++) { Wl[l] = (const float*)d_in[3 + 2 * l]; bl[l] = (const float*)d_in[4 + 2 * l]; }
    const int* src = ei;
    const int* dst = ei + E;
    (void)in_sizes; (void)n_in; (void)out_size;

    uintptr_t base = (uintptr_t)d_ws;
    uintptr_t cur = base;
    auto alloc = [&](size_t bytes) -> char* {
        uintptr_t q = (cur + 255) & ~(uintptr_t)255;
        cur = q + bytes;
        return (char*)q;
    };
    float* deg    = (float*)alloc((size_t)N * 4);
    float* dis    = (float*)alloc((size_t)N * 4);
    int*   rowptr = (int*)alloc((size_t)(N + 1) * 4);
    int*   cursor = (int*)alloc((size_t)N * 4);
    int2*  e2     = (int2*)alloc((size_t)E * 8);
    float* Zb     = (float*)alloc((size_t)(K + 1) * N * 4);  // [21, N] hop-major
    float* ya     = (float*)alloc((size_t)N * 4);
    float* yb     = (float*)alloc((size_t)N * 4);
    float* h1     = (float*)alloc((size_t)N * 64 * 4);   // stride 64 (padded, gathered)
    float* h2     = (float*)alloc((size_t)N * 100 * 4);
    float* h3     = (float*)alloc((size_t)N * 200 * 4);
    float* h4     = (float*)alloc((size_t)N * 80 * 4);
    float* Ra     = (float*)alloc((size_t)N * 96 * 4);   // stride 96 (padded, gathered)
    float* Rb     = (float*)alloc((size_t)N * 96 * 4);

    size_t used = (size_t)(cur - base);
    size_t reserve = (size_t)8 << 20;
    size_t avail = (ws_size > used + reserve) ? (ws_size - used - reserve) : 0;
    size_t cap = (size_t)N * 2000 * 4;
    size_t arena_bytes = avail < cap ? avail : cap;
    float* Sb = (float*)alloc(arena_bytes);
    unsigned short* WThi = (unsigned short*)alloc((size_t)2 << 20);
    unsigned short* WTmi = (unsigned short*)alloc((size_t)2 << 20);
    unsigned short* WTlo = (unsigned short*)alloc((size_t)2 << 20);
    // cap per-batch stack so it stays L3-resident (written -> read -> overwritten in cache)
    const size_t cacheCap = (size_t)128 << 20;
    size_t lim = arena_bytes < cacheCap ? arena_bytes : cacheCap;
    auto clampH = [&](int slotw, int hi) {
        long h = (long)(lim / ((size_t)N * slotw * 4));
        if (h < 1) h = 1;
        if (h > hi) h = hi;
        return (int)h;
    };
    const int H2s = clampH(64, K);       // -> 10 at 128 MB
    const int H3s = clampH(100, K);      // -> 6
    const int B4s = clampH(80, K + 1);   // -> 8
    const int rowstr2 = H2s * 64;
    const int rowstr3 = H3s * 100;
    const int rowstr4 = B4s * 80;

    // ---- CSR build
    hipMemsetAsync(deg, 0, (size_t)N * 4, stream);
    hipMemsetAsync(cursor, 0, (size_t)N * 4, stream);
    deg_count_kernel<<<(E + 255) / 256, 256, 0, stream>>>(src, dst, ew, deg, cursor, E);
    dis_kernel<<<(N + 255) / 256, 256, 0, stream>>>(deg, dis, N);
    scan_kernel<<<1, 1024, 0, stream>>>(cursor, rowptr, N);
    scatter_kernel<<<(E + 255) / 256, 256, 0, stream>>>(src, dst, ew, dis, cursor, e2, E);

    const int PB = (N + 63) / 64;
    const int P16 = (N + 15) / 16;   // propw2 LPN=16 blocks
    const int P32 = (N + 7) / 8;     // propw2 LPN=32 blocks
    const int GMX = (N + BM - 1) / BM;
    const int MGX = (N + MFM - 1) / MFM;
    auto gyf = [](int NC) { return (NC + BN - 1) / BN; };

    // ---- Layer 1 (1 -> 60): width-1 chain into Zb, one fp32 GEMM K=21
    hipMemcpyAsync(Zb, x, (size_t)N * 4, hipMemcpyDeviceToDevice, stream);
    for (int k = 1; k <= K; k++)
        prop1<<<PB, 256, 0, stream>>>(Zb + (size_t)(k - 1) * N, nullptr, Zb + (size_t)k * N,
                                      rowptr, e2, N, 0);
    gemm2<<<dim3(GMX, gyf(60)), 256, 0, stream>>>(Zb, 1, N, Wl[0], 60, 1, bl[0],
                                                  h1, 64, 1, N, K + 1, 60, GF_BIAS | GF_RELU, 60);

    // ---- Layer 2 (60 -> 100): h0 via MFMA (K padded 64), hop-batched stack + MFMA
    splitW_stack<<<(128 * 64 + 255) / 256, 256, 0, stream>>>(Wl[1], 0, 1, 60, 100, 64,
                                                             64, 128, WThi, WTmi, WTlo);
    gemm_mfma<<<dim3(MGX, 2), 256, 0, stream>>>(h1, 64, WThi, WTmi, WTlo, 64,
        bl[1], h2, 100, N, 64, 100, GF_BIAS, 100);
    {
        int done = 0;
        const float* prevp = h1; int prevstr = 64;
        while (done < K) {
            int H = (K - done < H2s) ? (K - done) : H2s;
            for (int j = 0; j < H; j++) {
                float* dstp = Sb + j * 64;
                propw2<16, 15, false, false><<<P16, 256, 0, stream>>>(prevp, prevstr, nullptr, 0,
                    dstp, rowstr2, rowptr, e2, N);
                prevp = dstp; prevstr = rowstr2;
            }
            int Kg = H * 64;
            int NCp = 128;
            int tot = NCp * Kg;
            splitW_stack<<<(tot + 255) / 256, 256, 0, stream>>>(Wl[1], 1 + done, H, 60, 100, 64,
                                                               Kg, NCp, WThi, WTmi, WTlo);
            bool last = (done + H == K);
            gemm_mfma<<<dim3(MGX, NCp / 64), 256, 0, stream>>>(Sb, rowstr2, WThi, WTmi, WTlo, Kg,
                nullptr, h2, 100, N, Kg, 100, GF_ACC | (last ? GF_RELU : 0), 0);
            done += H;
        }
    }

    // ---- Layer 3 (100 -> 200): h0 via MFMA (K padded 128), hop-batched stack + MFMA
    splitW_stack<<<(256 * 128 + 255) / 256, 256, 0, stream>>>(Wl[2], 0, 1, 100, 200, 128,
                                                              128, 256, WThi, WTmi, WTlo);
    gemm_mfma<<<dim3(MGX, 4), 256, 0, stream>>>(h2, 100, WThi, WTmi, WTlo, 128,
        bl[2], h3, 200, N, 128, 200, GF_BIAS, 200);
    {
        int done = 0;
        const float* prevp = h2; int prevstr = 100;
        while (done < K) {
            int H = (K - done < H3s) ? (K - done) : H3s;
            for (int j = 0; j < H; j++) {
                float* dstp = Sb + j * 100;
                propw2<32, 25, false, false><<<P32, 256, 0, stream>>>(prevp, prevstr, nullptr, 0,
                    dstp, rowstr3, rowptr, e2, N);
                prevp = dstp; prevstr = rowstr3;
            }
            int Kg = H * 100;
            int Kp = (Kg + 31) & ~31;
            int NCp = 256;
            int tot = NCp * Kp;
            splitW_stack<<<(tot + 255) / 256, 256, 0, stream>>>(Wl[2], 1 + done, H, 100, 200, 100,
                                                               Kp, NCp, WThi, WTmi, WTlo);
            bool last = (done + H == K);
            gemm_mfma<<<dim3(MGX, NCp / 64), 256, 0, stream>>>(Sb, rowstr3, WThi, WTmi, WTlo, Kp,
                nullptr, h3, 200, N, Kg, 200, GF_ACC | (last ? GF_RELU : 0), 0);
            done += H;
        }
    }

    // ---- Layer 4 (200 -> 80): batched Z pre-GEMM (MFMA) + Horner width-80
    {
        const float* curR = nullptr; int curstr = 0;
        int k_hi = K;
        while (k_hi >= 0) {
            int k_lo = k_hi - B4s + 1; if (k_lo < 0) k_lo = 0;
            int nb = k_hi - k_lo + 1;
            int NCp = ((nb * 80 + 63) / 64) * 64;
            int tot = NCp * 224;
            splitW_horner<<<(tot + 255) / 256, 256, 0, stream>>>(Wl[3], k_lo, nb, 224, NCp,
                                                                 WThi, WTmi, WTlo);
            gemm_mfma<<<dim3(MGX, NCp / 64), 256, 0, stream>>>(h3, 200, WThi, WTmi, WTlo, 224,
                bl[3], Sb, rowstr4, N, 200, nb * 80, (k_lo == 0) ? GF_BIAS : 0, 80);
            int kstart;
            if (k_hi == K) { curR = Sb + (size_t)(K - k_lo) * 80; curstr = rowstr4; kstart = K - 1; }
            else kstart = k_hi;
            for (int k = kstart; k >= k_lo; k--) {
                const float* Zp = Sb + (size_t)(k - k_lo) * 80;
                if (k == 0) {
                    propw2<32, 20, true, true><<<P32, 256, 0, stream>>>(curR, curstr, Zp, rowstr4,
                        h4, 80, rowptr, e2, N);
                } else {
                    float* o = (k & 1) ? Ra : Rb;
                    propw2<32, 20, true, false><<<P32, 256, 0, stream>>>(curR, curstr, Zp, rowstr4,
                        o, 96, rowptr, e2, N);
                    curR = o; curstr = 96;
                }
            }
            k_hi = k_lo - 1;
        }
    }

    // ---- Layer 5 (80 -> 1): Z5 [21, N] hop-major, Horner width-1 with sigmoid
    gemm2<<<dim3(GMX, gyf(21)), 256, 0, stream>>>(h4, 80, 1, Wl[4], 1, 80, bl[4],
                                                  Zb, 1, N, N, 80, K + 1, GF_BIAS, 1);
    const float* cur5 = Zb + (size_t)K * N;
    float* outp = (float*)d_out;
    for (int k = K - 1; k >= 0; k--) {
        float* o = (k == 0) ? outp : ((k & 1) ? ya : yb);
        prop1<<<PB, 256, 0, stream>>>(cur5, Zb + (size_t)k * N, o,
                                      rowptr, e2, N, (k == 0) ? 1 : 0);
        cur5 = o;
    }
}

// Round 10
// 4166.438 us; speedup vs baseline: 1.2878x; 1.0018x over previous
//
#include <hip/hip_runtime.h>
#include <stdint.h>

#define GF_ACC   1
#define GF_BIAS  2
#define GF_RELU  8

#define BM 128
#define BN 64
#define BK 16

typedef short bf16x8 __attribute__((ext_vector_type(8)));
typedef float f32x4 __attribute__((ext_vector_type(4)));
typedef unsigned short u16x8 __attribute__((ext_vector_type(8)));

// ---------------- CSR build ----------------

__global__ void deg_count_kernel(const int* __restrict__ src, const int* __restrict__ dst,
                                 const float* __restrict__ ew,
                                 float* __restrict__ deg, int* __restrict__ cnt, int E)
{
    int e = blockIdx.x * blockDim.x + threadIdx.x;
    if (e < E) {
        int d = dst[e];
        atomicAdd(&deg[d], ew[e]);
        atomicAdd(&cnt[d], 1);
    }
}

__global__ void dis_kernel(const float* __restrict__ deg, float* __restrict__ dis, int n)
{
    int i = blockIdx.x * blockDim.x + threadIdx.x;
    if (i < n) {
        float d = deg[i];
        dis[i] = (d > 0.f) ? (1.0f / sqrtf(d)) : 0.f;
    }
}

__global__ __launch_bounds__(1024) void scan_kernel(int* __restrict__ cnt_cursor,
                                                    int* __restrict__ row_ptr, int n)
{
    __shared__ int wsum[16];
    __shared__ int s_carry;
    if (threadIdx.x == 0) s_carry = 0;
    __syncthreads();
    const int VT = 8;
    const int CHUNK = 1024 * VT;
    int lane = threadIdx.x & 63;
    int wid = threadIdx.x >> 6;
    for (int base = 0; base < n; base += CHUNK) {
        int v[VT];
        int idx0 = base + threadIdx.x * VT;
        int tsum = 0;
#pragma unroll
        for (int t = 0; t < VT; t++) {
            int i = idx0 + t;
            v[t] = (i < n) ? cnt_cursor[i] : 0;
            tsum += v[t];
        }
        int incl = tsum;
        for (int off = 1; off < 64; off <<= 1) {
            int t = __shfl_up(incl, off);
            if (lane >= off) incl += t;
        }
        if (lane == 63) wsum[wid] = incl;
        __syncthreads();
        if (wid == 0) {
            int wv = (lane < 16) ? wsum[lane] : 0;
            for (int off = 1; off < 16; off <<= 1) {
                int t = __shfl_up(wv, off);
                if (lane >= off) wv += t;
            }
            if (lane < 16) wsum[lane] = wv;
        }
        __syncthreads();
        int wave_off = (wid > 0) ? wsum[wid - 1] : 0;
        int excl = incl - tsum + wave_off + s_carry;
#pragma unroll
        for (int t = 0; t < VT; t++) {
            int i = idx0 + t;
            if (i < n) {
                cnt_cursor[i] = excl;
                row_ptr[i + 1] = excl + v[t];
            }
            excl += v[t];
        }
        __syncthreads();
        if (threadIdx.x == 0) s_carry += wsum[15];
        __syncthreads();
    }
    if (threadIdx.x == 0) row_ptr[0] = 0;
}

__global__ void scatter_kernel(const int* __restrict__ src, const int* __restrict__ dst,
                               const float* __restrict__ ew, const float* __restrict__ dis,
                               int* __restrict__ cursor, int2* __restrict__ e2, int E)
{
    int e = blockIdx.x * blockDim.x + threadIdx.x;
    if (e < E) {
        int s = src[e], d = dst[e];
        int pos = atomicAdd(&cursor[d], 1);
        float nw = dis[s] * ew[e] * dis[d];
        e2[pos] = make_int2(s, __float_as_int(nw));
    }
}

// ---------------- propagation ----------------

__global__ __launch_bounds__(256) void prop1(const float* __restrict__ xv, const float* __restrict__ z,
                                             float* __restrict__ y, const int* __restrict__ rp,
                                             const int2* __restrict__ e2, int n, int mode)
{
    int node = blockIdx.x * 64 + (threadIdx.x >> 2);
    if (node >= n) return;
    int g = threadIdx.x & 3;
    int e0 = rp[node], e1 = rp[node + 1];
    float acc = 0.f;
    int e = e0 + g;
    for (; e + 4 < e1; e += 8) {
        int2 qa = e2[e];
        int2 qb = e2[e + 4];
        acc += __int_as_float(qa.y) * xv[qa.x];
        acc += __int_as_float(qb.y) * xv[qb.x];
    }
    if (e < e1) {
        int2 q = e2[e];
        acc += __int_as_float(q.y) * xv[q.x];
    }
    acc += __shfl_xor(acc, 1);
    acc += __shfl_xor(acc, 2);
    if (g == 0) {
        if (z) acc += z[node];
        if (mode == 1) acc = 1.0f / (1.0f + expf(-acc));
        y[node] = acc;
    }
}

// propw2: LPN lanes per node, each lane owns one float4 column group and loops edges 8-deep.
template<int LPN, int C4, bool HASZ, bool RELU>
__global__ __launch_bounds__(256) void propw2(const float* __restrict__ X, int xstr,
                                              const float* __restrict__ Z, int zstr,
                                              float* __restrict__ Y, int ystr,
                                              const int* __restrict__ rp,
                                              const int2* __restrict__ e2, int n)
{
    const int NPB = 256 / LPN;
    int node = blockIdx.x * NPB + threadIdx.x / LPN;
    if (node >= n) return;
    int c4 = threadIdx.x % LPN;
    bool colok = (c4 < C4);
    int cq = colok ? c4 : 0;
    int e0 = rp[node], e1 = rp[node + 1];
    float ax = 0.f, ay = 0.f, az = 0.f, aw = 0.f;
    int e = e0;
    for (; e + 8 <= e1; e += 8) {
        int2 q[8];
#pragma unroll
        for (int u = 0; u < 8; u++) q[u] = e2[e + u];
        float4 xq[8];
#pragma unroll
        for (int u = 0; u < 8; u++)
            xq[u] = *(const float4*)(X + (size_t)q[u].x * xstr + 4 * cq);
#pragma unroll
        for (int u = 0; u < 8; u++) {
            float wv = __int_as_float(q[u].y);
            ax += wv * xq[u].x; ay += wv * xq[u].y;
            az += wv * xq[u].z; aw += wv * xq[u].w;
        }
    }
    if (e < e1) {
#pragma unroll
        for (int u = 0; u < 8; u++) {
            int eid = e + u;
            int2 q = (eid < e1) ? e2[eid] : make_int2(0, 0);
            float4 xq = *(const float4*)(X + (size_t)q.x * xstr + 4 * cq);
            float wv = __int_as_float(q.y);
            ax += wv * xq.x; ay += wv * xq.y; az += wv * xq.z; aw += wv * xq.w;
        }
    }
    if (colok) {
        if (HASZ) {
            float4 zq = *(const float4*)(Z + (size_t)node * zstr + 4 * c4);
            ax += zq.x; ay += zq.y; az += zq.z; aw += zq.w;
        }
        if (RELU) {
            ax = fmaxf(ax, 0.f); ay = fmaxf(ay, 0.f);
            az = fmaxf(az, 0.f); aw = fmaxf(aw, 0.f);
        }
        float4 o = { ax, ay, az, aw };
        *(float4*)(Y + (size_t)node * ystr + 4 * c4) = o;
    }
}

// ---------------- fp32 GEMM (L1/L5 odd shapes; R3-proven config) ----------------

__global__ __launch_bounds__(256) void gemm2(
    const float* __restrict__ X, int x_sn, int x_sk,
    const float* __restrict__ W, int w_sk, int w_sc,
    const float* __restrict__ bias,
    float* __restrict__ out, int o_sn, int o_sc,
    int M, int K, int NC, int flags, int bias_cols)
{
    __shared__ float Xs[BK][BM + 4];
    __shared__ float Ws[BK][BN];
    int tid = threadIdx.x;
    int bm = blockIdx.x * BM;
    int bn = blockIdx.y * BN;
    int tx = tid & 15, ty = tid >> 4;
    float acc[8][4] = {};
    int xk = tid & 15, xm = tid >> 4;
    int wc = tid & 63, wk4 = tid >> 6;
    int vr = tid >> 2;
    int vc = (tid & 3) * 4;
    int wvk = tid >> 4;
    int wvc = (tid & 15) * 4;
    bool xvec = (x_sk == 1) && ((x_sn & 3) == 0) && (bm + BM <= M);
    bool wvec = (w_sc == 1) && ((w_sk & 3) == 0) && (bn + BN <= NC);
    for (int k0 = 0; k0 < K; k0 += BK) {
        bool fullk = (k0 + BK <= K);
        if (xvec && fullk) {
#pragma unroll
            for (int h = 0; h < 2; h++) {
                int m = vr + 64 * h;
                const float4 q = *(const float4*)(X + (size_t)(bm + m) * x_sn + k0 + vc);
                Xs[vc + 0][m] = q.x; Xs[vc + 1][m] = q.y;
                Xs[vc + 2][m] = q.z; Xs[vc + 3][m] = q.w;
            }
        } else {
#pragma unroll
            for (int r = 0; r < 8; r++) {
                int m = xm + 16 * r;
                int gm = bm + m, gk = k0 + xk;
                Xs[xk][m] = (gm < M && gk < K) ? X[(size_t)gm * x_sn + (size_t)gk * x_sk] : 0.f;
            }
        }
        if (wvec && fullk) {
            *(float4*)&Ws[wvk][wvc] = *(const float4*)(W + (size_t)(k0 + wvk) * w_sk + bn + wvc);
        } else {
#pragma unroll
            for (int r = 0; r < 4; r++) {
                int kk = wk4 + 4 * r;
                int gk = k0 + kk, gc = bn + wc;
                Ws[kk][wc] = (gk < K && gc < NC) ? W[(size_t)gk * w_sk + (size_t)gc * w_sc] : 0.f;
            }
        }
        __syncthreads();
#pragma unroll
        for (int kk = 0; kk < BK; kk++) {
            float xv[8], wv[4];
#pragma unroll
            for (int i = 0; i < 8; i++) xv[i] = Xs[kk][ty * 8 + i];
#pragma unroll
            for (int j = 0; j < 4; j++) wv[j] = Ws[kk][tx * 4 + j];
#pragma unroll
            for (int i = 0; i < 8; i++)
#pragma unroll
                for (int j = 0; j < 4; j++)
                    acc[i][j] += xv[i] * wv[j];
        }
        __syncthreads();
    }
    bool ovec = (o_sc == 1) && ((o_sn & 3) == 0) && (bn + tx * 4 + 3 < NC);
#pragma unroll
    for (int i = 0; i < 8; i++) {
        int gm = bm + ty * 8 + i;
        if (gm >= M) continue;
        if (ovec) {
            float* op = out + (size_t)gm * o_sn + bn + tx * 4;
            float4 v = { acc[i][0], acc[i][1], acc[i][2], acc[i][3] };
            if (flags & GF_ACC) {
                float4 o = *(const float4*)op;
                v.x += o.x; v.y += o.y; v.z += o.z; v.w += o.w;
            }
            if (flags & GF_BIAS) {
#pragma unroll
                for (int j = 0; j < 4; j++) {
                    int gc = bn + tx * 4 + j;
                    if (gc < bias_cols) (&v.x)[j] += bias[gc];
                }
            }
            if (flags & GF_RELU) {
                v.x = fmaxf(v.x, 0.f); v.y = fmaxf(v.y, 0.f);
                v.z = fmaxf(v.z, 0.f); v.w = fmaxf(v.w, 0.f);
            }
            *(float4*)op = v;
        } else {
#pragma unroll
            for (int j = 0; j < 4; j++) {
                int gc = bn + tx * 4 + j;
                if (gc >= NC) continue;
                size_t oi = (size_t)gm * o_sn + (size_t)gc * o_sc;
                float v = acc[i][j];
                if (flags & GF_ACC)  v += out[oi];
                if ((flags & GF_BIAS) && gc < bias_cols) v += bias[gc];
                if (flags & GF_RELU) v = fmaxf(v, 0.f);
                out[oi] = v;
            }
        }
    }
}

// ---------------- 3-term bf16 split (round-nearest, used for W prep) ----------------

__device__ __forceinline__ void bf16_split3(float v, unsigned short* h,
                                            unsigned short* m, unsigned short* l)
{
    unsigned u = __float_as_uint(v);
    unsigned uh = (u + 0x8000u) & 0xFFFF0000u;
    float fh = __uint_as_float(uh);
    float r1 = v - fh;
    unsigned u1 = __float_as_uint(r1);
    unsigned um = (u1 + 0x8000u) & 0xFFFF0000u;
    float fm = __uint_as_float(um);
    float r2 = r1 - fm;
    unsigned ul = (__float_as_uint(r2) + 0x8000u) & 0xFFFF0000u;
    *h = (unsigned short)(uh >> 16);
    *m = (unsigned short)(um >> 16);
    *l = (unsigned short)(ul >> 16);
}

// W [hops, Cin, Cout] -> WT h/m/l [NCpad, Kpad], n = cout, k = hop_slot*slot + c
__global__ void splitW_stack(const float* __restrict__ Wsrc, int hop0, int H,
                             int Cin, int Cout, int slot, int Kpad, int NCpad,
                             unsigned short* __restrict__ hi, unsigned short* __restrict__ mi,
                             unsigned short* __restrict__ lo)
{
    int t = blockIdx.x * blockDim.x + threadIdx.x;
    if (t >= NCpad * Kpad) return;
    int k = t % Kpad, n = t / Kpad;
    int j = k / slot, c = k % slot;
    float v = (n < Cout && j < H && c < Cin)
        ? Wsrc[((size_t)(hop0 + j) * Cin + c) * Cout + n] : 0.f;
    unsigned short h8, m8, l8;
    bf16_split3(v, &h8, &m8, &l8);
    hi[t] = h8; mi[t] = m8; lo[t] = l8;
}

// W4 [21, 200, 80] -> WT h/m/l [NCpad, Kpad], n = (hop-k_lo)*80 + co, k = cin
__global__ void splitW_horner(const float* __restrict__ W4, int k_lo, int nb,
                              int Kpad, int NCpad,
                              unsigned short* __restrict__ hi, unsigned short* __restrict__ mi,
                              unsigned short* __restrict__ lo)
{
    int t = blockIdx.x * blockDim.x + threadIdx.x;
    if (t >= NCpad * Kpad) return;
    int k = t % Kpad, n = t / Kpad;
    float v = 0.f;
    if (k < 200 && n < nb * 80) {
        int hop = k_lo + n / 80, co = n % 80;
        v = W4[(size_t)hop * 16000 + (size_t)k * 80 + co];
    }
    unsigned short h8, m8, l8;
    bf16_split3(v, &h8, &m8, &l8);
    hi[t] = h8; mi[t] = m8; lo[t] = l8;
}

// ---------------- MFMA GEMM (3-term split, 6 products, fp32 acc) ----------------
// MFN=128: one n-block covers NC<=128 so the A operand streams ONCE (R9 showed
// A re-streamed per 64-wide n-block was the GEMM's bandwidth clock).
#define MFM 128
#define MFN 128
#define ASTR 36
#define LSTR 40

__global__ __launch_bounds__(256) void gemm_mfma(
    const float* __restrict__ X, int x_sn,
    const unsigned short* __restrict__ Whi, const unsigned short* __restrict__ Wmi,
    const unsigned short* __restrict__ Wlo, int Kpad,
    const float* __restrict__ bias,
    float* __restrict__ out, int o_sn,
    int M, int K, int NC, int flags, int bias_cols)
{
    __shared__ float Af[MFM][ASTR];
    __shared__ unsigned short Bh[MFN][LSTR];
    __shared__ unsigned short Bm[MFN][LSTR];
    __shared__ unsigned short Bl[MFN][LSTR];
    int tid = threadIdx.x;
    int bm = blockIdx.x * MFM;
    int bn = blockIdx.y * MFN;
    int w = tid >> 6, lane = tid & 63;
    int q = lane >> 4, r = lane & 15;
    f32x4 acc[2][8];
#pragma unroll
    for (int a = 0; a < 2; a++)
#pragma unroll
        for (int b = 0; b < 8; b++)
            acc[a][b] = (f32x4){0.f, 0.f, 0.f, 0.f};
    int sm = tid >> 1;
    int skq = (tid & 1) * 16;
    int bnr = tid >> 1;           // 0..127 B row
    int bkq = (tid & 1) * 16;     // 0 / 16 ushort offset
    const float* xbase = X + (size_t)(bm + sm) * x_sn + skq;
    int ksteps = (K + 31) / 32;
    for (int ks = 0; ks < ksteps; ks++) {
        int k0 = ks * 32;
#pragma unroll
        for (int h = 0; h < 4; h++)
            *(float4*)&Af[sm][skq + 4 * h] = *(const float4*)(xbase + k0 + 4 * h);
        size_t wo = (size_t)(bn + bnr) * Kpad + k0 + bkq;
        *(u16x8*)&Bh[bnr][bkq]     = *(const u16x8*)(Whi + wo);
        *(u16x8*)&Bh[bnr][bkq + 8] = *(const u16x8*)(Whi + wo + 8);
        *(u16x8*)&Bm[bnr][bkq]     = *(const u16x8*)(Wmi + wo);
        *(u16x8*)&Bm[bnr][bkq + 8] = *(const u16x8*)(Wmi + wo + 8);
        *(u16x8*)&Bl[bnr][bkq]     = *(const u16x8*)(Wlo + wo);
        *(u16x8*)&Bl[bnr][bkq + 8] = *(const u16x8*)(Wlo + wo + 8);
        __syncthreads();
#pragma unroll
        for (int mt = 0; mt < 2; mt++) {
            int arow = w * 32 + mt * 16 + r;
            float4 fa = *(const float4*)&Af[arow][q * 8];
            float4 fb = *(const float4*)&Af[arow][q * 8 + 4];
            float vf[8] = { fa.x, fa.y, fa.z, fa.w, fb.x, fb.y, fb.z, fb.w };
            bf16x8 ah, am, al;
#pragma unroll
            for (int j = 0; j < 8; j++) {
                float v = vf[j];
                unsigned u = __float_as_uint(v);
                unsigned uh = u & 0xFFFF0000u;
                float r1 = v - __uint_as_float(uh);
                unsigned u1 = __float_as_uint(r1);
                unsigned um = u1 & 0xFFFF0000u;
                float r2 = r1 - __uint_as_float(um);
                ah[j] = (short)(uh >> 16);
                am[j] = (short)(um >> 16);
                al[j] = (short)(__float_as_uint(r2) >> 16);
            }
#pragma unroll
            for (int nt = 0; nt < 8; nt++) {
                bf16x8 bh = *(const bf16x8*)&Bh[nt * 16 + r][q * 8];
                bf16x8 bm2 = *(const bf16x8*)&Bm[nt * 16 + r][q * 8];
                bf16x8 bl = *(const bf16x8*)&Bl[nt * 16 + r][q * 8];
                acc[mt][nt] = __builtin_amdgcn_mfma_f32_16x16x32_bf16(al, bh, acc[mt][nt], 0, 0, 0);
                acc[mt][nt] = __builtin_amdgcn_mfma_f32_16x16x32_bf16(ah, bl, acc[mt][nt], 0, 0, 0);
                acc[mt][nt] = __builtin_amdgcn_mfma_f32_16x16x32_bf16(am, bm2, acc[mt][nt], 0, 0, 0);
                acc[mt][nt] = __builtin_amdgcn_mfma_f32_16x16x32_bf16(am, bh, acc[mt][nt], 0, 0, 0);
                acc[mt][nt] = __builtin_amdgcn_mfma_f32_16x16x32_bf16(ah, bm2, acc[mt][nt], 0, 0, 0);
                acc[mt][nt] = __builtin_amdgcn_mfma_f32_16x16x32_bf16(ah, bh, acc[mt][nt], 0, 0, 0);
            }
        }
        __syncthreads();
    }
#pragma unroll
    for (int mt = 0; mt < 2; mt++) {
#pragma unroll
        for (int i = 0; i < 4; i++) {
            int gm = bm + w * 32 + mt * 16 + q * 4 + i;
            if (gm >= M) continue;
#pragma unroll
            for (int nt = 0; nt < 8; nt++) {
                int gc = bn + nt * 16 + r;
                if (gc >= NC) continue;
                size_t oi = (size_t)gm * o_sn + gc;
                float v = acc[mt][nt][i];
                if (flags & GF_ACC)  v += out[oi];
                if ((flags & GF_BIAS) && gc < bias_cols) v += bias[gc];
                if (flags & GF_RELU) v = fmaxf(v, 0.f);
                out[oi] = v;
            }
        }
    }
}

// ---------------- launch ----------------

extern "C" void kernel_launch(void* const* d_in, const int* in_sizes, int n_in,
                              void* d_out, int out_size, void* d_ws, size_t ws_size,
                              hipStream_t stream)
{
    const int N = 50000, E = 800000, K = 20;
    const float* x  = (const float*)d_in[0];
    const int*   ei = (const int*)d_in[1];
    const float* ew = (const float*)d_in[2];
    const float* Wl[5]; const float* bl[5];
    for (int l = 0; l < 5; l++) { Wl[l] = (const float*)d_in[3 + 2 * l]; bl[l] = (const float*)d_in[4 + 2 * l]; }
    const int* src = ei;
    const int* dst = ei + E;
    (void)in_sizes; (void)n_in; (void)out_size;

    uintptr_t base = (uintptr_t)d_ws;
    uintptr_t cur = base;
    auto alloc = [&](size_t bytes) -> char* {
        uintptr_t q = (cur + 255) & ~(uintptr_t)255;
        cur = q + bytes;
        return (char*)q;
    };
    float* deg    = (float*)alloc((size_t)N * 4);
    float* dis    = (float*)alloc((size_t)N * 4);
    int*   rowptr = (int*)alloc((size_t)(N + 1) * 4);
    int*   cursor = (int*)alloc((size_t)N * 4);
    int2*  e2     = (int2*)alloc((size_t)E * 8);
    float* Zb     = (float*)alloc((size_t)(K + 1) * N * 4);  // [21, N] hop-major
    float* ya     = (float*)alloc((size_t)N * 4);
    float* yb     = (float*)alloc((size_t)N * 4);
    float* h1     = (float*)alloc((size_t)N * 64 * 4);   // stride 64 (padded, gathered)
    float* h2     = (float*)alloc((size_t)N * 100 * 4);
    float* h3     = (float*)alloc((size_t)N * 200 * 4);
    float* h4     = (float*)alloc((size_t)N * 80 * 4);
    float* Ra     = (float*)alloc((size_t)N * 96 * 4);   // stride 96 (padded, gathered)
    float* Rb     = (float*)alloc((size_t)N * 96 * 4);

    size_t used = (size_t)(cur - base);
    size_t reserve = (size_t)8 << 20;
    size_t avail = (ws_size > used + reserve) ? (ws_size - used - reserve) : 0;
    size_t cap = (size_t)N * 2000 * 4;
    size_t arena_bytes = avail < cap ? avail : cap;
    float* Sb = (float*)alloc(arena_bytes);
    unsigned short* WThi = (unsigned short*)alloc((size_t)2 << 20);
    unsigned short* WTmi = (unsigned short*)alloc((size_t)2 << 20);
    unsigned short* WTlo = (unsigned short*)alloc((size_t)2 << 20);
    const size_t cacheCap = (size_t)128 << 20;
    size_t lim = arena_bytes < cacheCap ? arena_bytes : cacheCap;
    auto clampH = [&](int slotw, int hi) {
        long h = (long)(lim / ((size_t)N * slotw * 4));
        if (h < 1) h = 1;
        if (h > hi) h = hi;
        return (int)h;
    };
    const int H2s = clampH(64, K);       // -> 10
    const int H3s = clampH(100, K);      // -> 6
    const int B4s = clampH(80, K + 1);   // -> 8
    const int rowstr2 = H2s * 64;
    const int rowstr3 = H3s * 100;
    const int rowstr4 = B4s * 80;

    // ---- CSR build
    hipMemsetAsync(deg, 0, (size_t)N * 4, stream);
    hipMemsetAsync(cursor, 0, (size_t)N * 4, stream);
    deg_count_kernel<<<(E + 255) / 256, 256, 0, stream>>>(src, dst, ew, deg, cursor, E);
    dis_kernel<<<(N + 255) / 256, 256, 0, stream>>>(deg, dis, N);
    scan_kernel<<<1, 1024, 0, stream>>>(cursor, rowptr, N);
    scatter_kernel<<<(E + 255) / 256, 256, 0, stream>>>(src, dst, ew, dis, cursor, e2, E);

    const int PB = (N + 63) / 64;
    const int P16 = (N + 15) / 16;
    const int P32 = (N + 7) / 8;
    const int GMX = (N + BM - 1) / BM;
    const int MGX = (N + MFM - 1) / MFM;
    auto gyf = [](int NC) { return (NC + BN - 1) / BN; };

    // ---- Layer 1 (1 -> 60): width-1 chain into Zb, one fp32 GEMM K=21
    hipMemcpyAsync(Zb, x, (size_t)N * 4, hipMemcpyDeviceToDevice, stream);
    for (int k = 1; k <= K; k++)
        prop1<<<PB, 256, 0, stream>>>(Zb + (size_t)(k - 1) * N, nullptr, Zb + (size_t)k * N,
                                      rowptr, e2, N, 0);
    gemm2<<<dim3(GMX, gyf(60)), 256, 0, stream>>>(Zb, 1, N, Wl[0], 60, 1, bl[0],
                                                  h1, 64, 1, N, K + 1, 60, GF_BIAS | GF_RELU, 60);

    // ---- Layer 2 (60 -> 100): h0 via MFMA (K padded 64), hop-batched stack + MFMA
    splitW_stack<<<(128 * 64 + 255) / 256, 256, 0, stream>>>(Wl[1], 0, 1, 60, 100, 64,
                                                             64, 128, WThi, WTmi, WTlo);
    gemm_mfma<<<dim3(MGX, 1), 256, 0, stream>>>(h1, 64, WThi, WTmi, WTlo, 64,
        bl[1], h2, 100, N, 64, 100, GF_BIAS, 100);
    {
        int done = 0;
        const float* prevp = h1; int prevstr = 64;
        while (done < K) {
            int H = (K - done < H2s) ? (K - done) : H2s;
            for (int j = 0; j < H; j++) {
                float* dstp = Sb + j * 64;
                propw2<16, 15, false, false><<<P16, 256, 0, stream>>>(prevp, prevstr, nullptr, 0,
                    dstp, rowstr2, rowptr, e2, N);
                prevp = dstp; prevstr = rowstr2;
            }
            int Kg = H * 64;
            int NCp = 128;
            int tot = NCp * Kg;
            splitW_stack<<<(tot + 255) / 256, 256, 0, stream>>>(Wl[1], 1 + done, H, 60, 100, 64,
                                                               Kg, NCp, WThi, WTmi, WTlo);
            bool last = (done + H == K);
            gemm_mfma<<<dim3(MGX, 1), 256, 0, stream>>>(Sb, rowstr2, WThi, WTmi, WTlo, Kg,
                nullptr, h2, 100, N, Kg, 100, GF_ACC | (last ? GF_RELU : 0), 0);
            done += H;
        }
    }

    // ---- Layer 3 (100 -> 200): h0 via MFMA (K padded 128), hop-batched stack + MFMA
    splitW_stack<<<(256 * 128 + 255) / 256, 256, 0, stream>>>(Wl[2], 0, 1, 100, 200, 128,
                                                              128, 256, WThi, WTmi, WTlo);
    gemm_mfma<<<dim3(MGX, 2), 256, 0, stream>>>(h2, 100, WThi, WTmi, WTlo, 128,
        bl[2], h3, 200, N, 128, 200, GF_BIAS, 200);
    {
        int done = 0;
        const float* prevp = h2; int prevstr = 100;
        while (done < K) {
            int H = (K - done < H3s) ? (K - done) : H3s;
            for (int j = 0; j < H; j++) {
                float* dstp = Sb + j * 100;
                propw2<32, 25, false, false><<<P32, 256, 0, stream>>>(prevp, prevstr, nullptr, 0,
                    dstp, rowstr3, rowptr, e2, N);
                prevp = dstp; prevstr = rowstr3;
            }
            int Kg = H * 100;
            int Kp = (Kg + 31) & ~31;
            int NCp = 256;
            int tot = NCp * Kp;
            splitW_stack<<<(tot + 255) / 256, 256, 0, stream>>>(Wl[2], 1 + done, H, 100, 200, 100,
                                                               Kp, NCp, WThi, WTmi, WTlo);
            bool last = (done + H == K);
            gemm_mfma<<<dim3(MGX, 2), 256, 0, stream>>>(Sb, rowstr3, WThi, WTmi, WTlo, Kp,
                nullptr, h3, 200, N, Kg, 200, GF_ACC | (last ? GF_RELU : 0), 0);
            done += H;
        }
    }

    // ---- Layer 4 (200 -> 80): batched Z pre-GEMM (MFMA) + Horner width-80
    {
        const float* curR = nullptr; int curstr = 0;
        int k_hi = K;
        while (k_hi >= 0) {
            int k_lo = k_hi - B4s + 1; if (k_lo < 0) k_lo = 0;
            int nb = k_hi - k_lo + 1;
            int NCp = ((nb * 80 + 127) / 128) * 128;
            int tot = NCp * 224;
            splitW_horner<<<(tot + 255) / 256, 256, 0, stream>>>(Wl[3], k_lo, nb, 224, NCp,
                                                                 WThi, WTmi, WTlo);
            gemm_mfma<<<dim3(MGX, NCp / 128), 256, 0, stream>>>(h3, 200, WThi, WTmi, WTlo, 224,
                bl[3], Sb, rowstr4, N, 200, nb * 80, (k_lo == 0) ? GF_BIAS : 0, 80);
            int kstart;
            if (k_hi == K) { curR = Sb + (size_t)(K - k_lo) * 80; curstr = rowstr4; kstart = K - 1; }
            else kstart = k_hi;
            for (int k = kstart; k >= k_lo; k--) {
                const float* Zp = Sb + (size_t)(k - k_lo) * 80;
                if (k == 0) {
                    propw2<32, 20, true, true><<<P32, 256, 0, stream>>>(curR, curstr, Zp, rowstr4,
                        h4, 80, rowptr, e2, N);
                } else {
                    float* o = (k & 1) ? Ra : Rb;
                    propw2<32, 20, true, false><<<P32, 256, 0, stream>>>(curR, curstr, Zp, rowstr4,
                        o, 96, rowptr, e2, N);
                    curR = o; curstr = 96;
                }
            }
            k_hi = k_lo - 1;
        }
    }

    // ---- Layer 5 (80 -> 1): Z5 [21, N] hop-major, Horner width-1 with sigmoid
    gemm2<<<dim3(GMX, gyf(21)), 256, 0, stream>>>(h4, 80, 1, Wl[4], 1, 80, bl[4],
                                                  Zb, 1, N, N, 80, K + 1, GF_BIAS, 1);
    const float* cur5 = Zb + (size_t)K * N;
    float* outp = (float*)d_out;
    for (int k = K - 1; k >= 0; k--) {
        float* o = (k == 0) ? outp : ((k & 1) ? ya : yb);
        prop1<<<PB, 256, 0, stream>>>(cur5, Zb + (size_t)k * N, o,
                                      rowptr, e2, N, (k == 0) ? 1 : 0);
        cur5 = o;
    }
}